// Round 10
// baseline (730.566 us; speedup 1.0000x reference)
//
#include <hip/hip_runtime.h>

#define NN 20000
#define NE 320000
#define NL 3
#define NP 8192
#define EDIM 9
#define TROWS 32
#define MAXT 272
#define CAPR (MAXT*TROWS)

typedef _Float16 f16x8 __attribute__((ext_vector_type(8)));
typedef float f32x4 __attribute__((ext_vector_type(4)));

#define GLL16(g,l) __builtin_amdgcn_global_load_lds((const __attribute__((address_space(1))) unsigned int*)(g), (__attribute__((address_space(3))) unsigned int*)(l), 16, 0, 0)

__device__ __forceinline__ float sigm(float x){ return 1.f/(1.f+__expf(-x)); }

template<int CTRL>
__device__ __forceinline__ float dpp_mov(float x){
  return __int_as_float(__builtin_amdgcn_update_dpp(0, __float_as_int(x), CTRL, 0xf, 0xf, true));
}
// all-lanes sum within each 16-lane row (DPP butterfly, no LDS pipe)
__device__ __forceinline__ float row_allsum16(float x, int l){
  x += dpp_mov<0xB1>(x);
  x += dpp_mov<0x4E>(x);
  float a4=dpp_mov<0x104>(x), b4=dpp_mov<0x114>(x);
  x += (l&4)? b4 : a4;
  float a8=dpp_mov<0x108>(x), b8=dpp_mov<0x118>(x);
  x += (l&8)? b8 : a8;
  return x;
}

__device__ __forceinline__ float4 f4fma(float s, float4 a, float4 b){
  return make_float4(fmaf(s,a.x,b.x), fmaf(s,a.y,b.y), fmaf(s,a.z,b.z), fmaf(s,a.w,b.w));
}

__global__ void k_fill_i(int* __restrict__ p, int n, int v){ int i=blockIdx.x*blockDim.x+threadIdx.x; if(i<n)p[i]=v; }

__global__ void k_deg(const int* __restrict__ ei, int* __restrict__ deg){
  int e=blockIdx.x*blockDim.x+threadIdx.x; if(e<NE) atomicAdd(&deg[ei[NE+e]],1);
}

__global__ __launch_bounds__(1024) void k_scan(const int* __restrict__ deg, int* __restrict__ row_ptr, int* __restrict__ cursor){
  __shared__ int sh[1024];
  __shared__ int carry;
  int tid=threadIdx.x;
  if(tid==0) carry=0;
  __syncthreads();
  for(int base=0;base<NN;base+=1024){
    int i=base+tid;
    int v=(i<NN)?deg[i]:0;
    sh[tid]=v; __syncthreads();
    for(int o=1;o<1024;o<<=1){
      int t=(tid>=o)?sh[tid-o]:0; __syncthreads();
      sh[tid]+=t; __syncthreads();
    }
    int incl=sh[tid];
    int c=carry;
    if(i<NN){ row_ptr[i+1]=c+incl; cursor[i]=c+incl-v; }
    if(i==0) row_ptr[0]=0;
    __syncthreads();
    if(tid==1023) carry=c+incl;
    __syncthreads();
  }
}

// CSR fill with source-node + edge-attr materialized in slot order
__global__ void k_fill_csr2(const int* __restrict__ ei, const float* __restrict__ ea,
    int* __restrict__ cursor, int* __restrict__ csr_src, float* __restrict__ eas){
  int e=blockIdx.x*blockDim.x+threadIdx.x;
  if(e<NE){
    int t=ei[NE+e]; int pos=atomicAdd(&cursor[t],1);
    csr_src[pos]=ei[e];
    const float* s=ea+(size_t)e*9;
    float* d=eas+(size_t)pos*12;
    #pragma unroll
    for(int k=0;k<9;++k) d[k]=s[k];
    d[9]=0.f; d[10]=0.f; d[11]=0.f;
  }
}

// stable counting-sort of pairs by type; tiles of 32 rows padded per group; islot = slot->output pos
__global__ __launch_bounds__(256) void k_sort(const int* __restrict__ types, int* __restrict__ meta,
    int* __restrict__ slotp, int* __restrict__ islot){
  __shared__ int cnt[256][8];
  __shared__ int tot[8];
  __shared__ int base_s[8], pad_s[8];
  int tid=threadIdx.x;
  int lc[8]={0,0,0,0,0,0,0,0};
  int tl[32];
  for(int i=0;i<32;++i){ int ty=types[tid*32+i]; tl[i]=ty; lc[ty]++; }
  #pragma unroll
  for(int t=0;t<8;++t) cnt[tid][t]=lc[t];
  __syncthreads();
  if(tid<8){
    int run=0;
    for(int j=0;j<256;++j){ int v=cnt[j][tid]; cnt[j][tid]=run; run+=v; }
    tot[tid]=run;
  }
  __syncthreads();
  if(tid==0){
    int b=0, pb=0, nt=0;
    for(int t=0;t<8;++t){
      base_s[t]=b; pad_s[t]=pb;
      meta[t]=tot[t]; meta[8+t]=b; meta[16+t]=pb;
      int ntt=(tot[t]+31)>>5;
      for(int j=0;j<ntt;++j){ meta[32+nt]=t; meta[32+MAXT+nt]=pb+j*32; nt++; }
      b+=tot[t]; pb+=ntt*32;
    }
    meta[24]=nt; meta[25]=pb;
  }
  __syncthreads();
  if(tid<8){
    int t=tid; int ntt=(tot[t]+31)>>5;
    for(int sr=tot[t]; sr<ntt*32; ++sr) islot[pad_s[t]+sr]=-1;
  }
  int run[8];
  #pragma unroll
  for(int t=0;t<8;++t) run[t]=cnt[tid][t];
  for(int i=0;i<32;++i){
    int p=tid*32+i; int t=tl[i]; int r=run[t]++;
    int pos=base_s[t]+r, slot=pad_s[t]+r;
    slotp[p]=slot; islot[slot]=pos;
  }
}

// xl = lrelu?(hin)@Wl + bl ; xr = lrelu?(hin)@Wr + br   (K=64, out 256 each)
__global__ __launch_bounds__(256) void k_nodexf(const float* __restrict__ hin,
    const float* __restrict__ Wl, const float* __restrict__ bl,
    const float* __restrict__ Wr, const float* __restrict__ br,
    float* __restrict__ xl, float* __restrict__ xr, int lk){
  __shared__ float hs[64][66];
  __shared__ float ws[64][66];
  int n0=blockIdx.x*64, tid=threadIdx.x;
  for(int idx=tid; idx<64*64; idx+=256){
    int r=idx>>6,k=idx&63; int n=n0+r;
    float v=(n<NN)?hin[(size_t)n*64+k]:0.f;
    if(lk) v=v>0.f?v:0.01f*v;
    hs[r][k]=v;
  }
  int ty=tid>>4, tx=tid&15;
  for(int ch=0; ch<8; ++ch){
    const float* W=(ch<4)?Wl:Wr;
    const float* bb=(ch<4)?bl:br;
    float* outp=(ch<4)?xl:xr;
    int c0=(ch&3)*64;
    __syncthreads();
    for(int idx=tid; idx<64*64; idx+=256){ int k=idx>>6,j=idx&63; ws[k][j]=W[(size_t)k*256+c0+j]; }
    __syncthreads();
    float acc[4][4]={};
    #pragma unroll 4
    for(int k=0;k<64;++k){
      float a0=hs[4*ty+0][k],a1=hs[4*ty+1][k],a2=hs[4*ty+2][k],a3=hs[4*ty+3][k];
      float b0=ws[k][4*tx+0],b1v=ws[k][4*tx+1],b2v=ws[k][4*tx+2],b3v=ws[k][4*tx+3];
      acc[0][0]+=a0*b0; acc[0][1]+=a0*b1v; acc[0][2]+=a0*b2v; acc[0][3]+=a0*b3v;
      acc[1][0]+=a1*b0; acc[1][1]+=a1*b1v; acc[1][2]+=a1*b2v; acc[1][3]+=a1*b3v;
      acc[2][0]+=a2*b0; acc[2][1]+=a2*b1v; acc[2][2]+=a2*b2v; acc[2][3]+=a2*b3v;
      acc[3][0]+=a3*b0; acc[3][1]+=a3*b1v; acc[3][2]+=a3*b2v; acc[3][3]+=a3*b3v;
    }
    #pragma unroll
    for(int i=0;i<4;++i){
      int n=n0+4*ty+i;
      if(n<NN){
        #pragma unroll
        for(int j=0;j<4;++j){ int c=c0+4*tx+j; outp[(size_t)n*256+c]=acc[i][j]+bb[c]; }
      }
    }
  }
}

// fused GAT edge pipeline v4: one WAVE owns one node, covers all 4 heads;
// walks the full edge list with depth-4 rolling xl prefetch. No loop LDS/syncs.
__global__ __launch_bounds__(256) void k_agg4(const float* __restrict__ xl, const float* __restrict__ xr,
    const float* __restrict__ eas, const int* __restrict__ csr_src, const int* __restrict__ row_ptr,
    const float* __restrict__ WeL, const float* __restrict__ attL,
    const float* __restrict__ biasL, const float* __restrict__ gates, int layer,
    const float* __restrict__ hprev, float* __restrict__ hout){
  int n=blockIdx.x*4+(threadIdx.x>>6);
  int l=threadIdx.x&63;
  int cg=l&15;
  int ch0=(l>>4)*64+cg*4;
  float4 Wk[9];
  #pragma unroll
  for(int k=0;k<9;++k) Wk[k]=*(const float4*)&WeL[k*256+ch0];
  float4 att=*(const float4*)&attL[ch0];
  float4 xr4=*(const float4*)&xr[(size_t)n*256+ch0];
  int s=row_ptr[n], t=row_ptr[n+1];
  float den=0.f;
  float4 acc=make_float4(0.f,0.f,0.f,0.f);

  auto body=[&](float4 xc, int j){
    const float* ej=eas+(size_t)j*12;
    float4 e0=*(const float4*)ej;
    float4 e1=*(const float4*)(ej+4);
    float e8=ej[8];
    float4 m=make_float4(xc.x+xr4.x, xc.y+xr4.y, xc.z+xr4.z, xc.w+xr4.w);
    m=f4fma(e0.x,Wk[0],m); m=f4fma(e0.y,Wk[1],m); m=f4fma(e0.z,Wk[2],m);
    m=f4fma(e0.w,Wk[3],m); m=f4fma(e1.x,Wk[4],m); m=f4fma(e1.y,Wk[5],m);
    m=f4fma(e1.z,Wk[6],m); m=f4fma(e1.w,Wk[7],m); m=f4fma(e8 ,Wk[8],m);
    m.x=fmaxf(m.x,0.f)+0.2f*fminf(m.x,0.f);
    m.y=fmaxf(m.y,0.f)+0.2f*fminf(m.y,0.f);
    m.z=fmaxf(m.z,0.f)+0.2f*fminf(m.z,0.f);
    m.w=fmaxf(m.w,0.f)+0.2f*fminf(m.w,0.f);
    float pl=fmaf(m.x,att.x, fmaf(m.y,att.y, fmaf(m.z,att.z, m.w*att.w)));
    float pt=row_allsum16(pl,l);
    float a=__expf(pt);
    den+=a;
    acc=f4fma(a,xc,acc);
  };

  float4 z4=make_float4(0.f,0.f,0.f,0.f);
  float4 x0=z4,x1=z4,x2=z4,x3=z4;
  if(s+0<t) x0=*(const float4*)&xl[(size_t)csr_src[s+0]*256+ch0];
  if(s+1<t) x1=*(const float4*)&xl[(size_t)csr_src[s+1]*256+ch0];
  if(s+2<t) x2=*(const float4*)&xl[(size_t)csr_src[s+2]*256+ch0];
  if(s+3<t) x3=*(const float4*)&xl[(size_t)csr_src[s+3]*256+ch0];
  int j=s;
  while(j+7<t){
    float4 y0=*(const float4*)&xl[(size_t)csr_src[j+4]*256+ch0];
    float4 y1=*(const float4*)&xl[(size_t)csr_src[j+5]*256+ch0];
    float4 y2=*(const float4*)&xl[(size_t)csr_src[j+6]*256+ch0];
    float4 y3=*(const float4*)&xl[(size_t)csr_src[j+7]*256+ch0];
    body(x0,j); body(x1,j+1); body(x2,j+2); body(x3,j+3);
    x0=y0; x1=y1; x2=y2; x3=y3;
    j+=4;
  }
  if(j<t){ body(x0,j); ++j; }
  if(j<t){ body(x1,j); ++j; }
  if(j<t){ body(x2,j); ++j; }
  if(j<t){ body(x3,j); ++j; }
  while(j<t){ body(*(const float4*)&xl[(size_t)csr_src[j]*256+ch0], j); ++j; }

  // head-mean epilogue: scale by 1/den (uniform within 16-lane head group),
  // sum across heads via xor-16/32 shuffles, lanes 0..15 write 4 channels each.
  float rdn=den>0.f?1.f/den:0.f;
  float4 v=make_float4(acc.x*rdn, acc.y*rdn, acc.z*rdn, acc.w*rdn);
  v.x+=__shfl_xor(v.x,16); v.y+=__shfl_xor(v.y,16); v.z+=__shfl_xor(v.z,16); v.w+=__shfl_xor(v.w,16);
  v.x+=__shfl_xor(v.x,32); v.y+=__shfl_xor(v.y,32); v.z+=__shfl_xor(v.z,32); v.w+=__shfl_xor(v.w,32);
  if(l<16){
    float4 b4=*(const float4*)&biasL[cg*4];
    float4 o=make_float4(v.x*0.25f+b4.x, v.y*0.25f+b4.y, v.z*0.25f+b4.z, v.w*0.25f+b4.w);
    if(layer>0){
      float4 hp=*(const float4*)&hprev[(size_t)n*64+cg*4];
      hp.x=hp.x>0.f?hp.x:0.01f*hp.x; hp.y=hp.y>0.f?hp.y:0.01f*hp.y;
      hp.z=hp.z>0.f?hp.z:0.01f*hp.z; hp.w=hp.w>0.f?hp.w:0.01f*hp.w;
      float g=sigm(gates[layer-1]);
      o=make_float4(g*o.x+(1.f-g)*hp.x, g*o.y+(1.f-g)*hp.y, g*o.z+(1.f-g)*hp.z, g*o.w+(1.f-g)*hp.w);
    }
    *(float4*)&hout[(size_t)n*64+cg*4]=o;
  }
}

// z0[slot, 2c]=h[a,c], z0[slot,2c+1]=h[b,c]
__global__ void k_buildz(const float* __restrict__ hfin, const int* __restrict__ ecross,
    const int* __restrict__ slotp, float* __restrict__ z){
  int g=blockIdx.x*blockDim.x+threadIdx.x;
  if(g>=NP*64) return;
  int p=g>>6, c=g&63;
  int a=ecross[2*p], b=ecross[2*p+1];
  int slot=slotp[p];
  float2 v; v.x=hfin[(size_t)a*64+c]; v.y=hfin[(size_t)b*64+c];
  ((float2*)(z+(size_t)slot*128))[c]=v;
}

// W1 prep: per (er, chunk of 32 j): chunk-linear fp16 image [jl(32)][k(128)] with
// XOR swizzle ((jl*128+k) ^ ((jl&7)<<3)) baked in -> global_load_lds drops it verbatim.
__global__ __launch_bounds__(256) void k_prepw1(const float* __restrict__ src, _Float16* __restrict__ dst){
  __shared__ float lds[128][33];
  int bid=blockIdx.x, er=bid>>7, ch=bid&127;
  const float* s=src+(size_t)er*128*4096 + ch*32;
  int tid=threadIdx.x;
  for(int idx=tid; idx<128*32; idx+=256){ int k=idx>>5, jl=idx&31; lds[k][jl]=s[(size_t)k*4096+jl]; }
  __syncthreads();
  _Float16* d=dst+(size_t)bid*4096;
  for(int g=tid; g<512; g+=256){
    int jl=g>>4, k8=g&15;
    f16x8 v;
    #pragma unroll
    for(int t=0;t<8;++t) v[t]=(_Float16)lds[k8*8+t][jl];
    int elem=(jl*128+k8*8)^((jl&7)<<3);
    *(f16x8*)(&d[elem])=v;
  }
}

// W2 prep: per (er, chunk of 32 j): [n(128)][jl(32)] with XOR swizzle ((n*32+jl) ^ ((n&7)<<3)).
__global__ __launch_bounds__(256) void k_prepw2(const float* __restrict__ src, _Float16* __restrict__ dst){
  __shared__ float lds[32][130];
  int bid=blockIdx.x, er=bid>>7, ch=bid&127;
  const float* s=src+(size_t)er*4096*128 + (size_t)ch*32*128;
  int tid=threadIdx.x;
  for(int idx=tid; idx<32*128; idx+=256){ int j=idx>>7, n=idx&127; lds[j][n]=s[(size_t)j*128+n]; }
  __syncthreads();
  _Float16* d=dst+(size_t)bid*4096;
  for(int g=tid; g<512; g+=256){
    int n=g>>2, j8=g&3;
    f16x8 v;
    #pragma unroll
    for(int t=0;t<8;++t) v[t]=(_Float16)lds[j8*8+t][n];
    int elem=(n*32+j8*8)^((n&7)<<3);
    *(f16x8*)(&d[elem])=v;
  }
}

// MFMA res-block partial: ypart[hq] = relu(relu(z)@W1[:,hq-range]+b1) @ W2[hq-range,:]
__global__ __launch_bounds__(256) void k_resmfma(const float* __restrict__ zin,
    const _Float16* __restrict__ w1t, const _Float16* __restrict__ w2t,
    const float* __restrict__ b1all, const int* __restrict__ meta,
    float* __restrict__ ypart, int rb)
{
  __shared__ _Float16 zh[32*128];
  __shared__ _Float16 wb[2][8192];
  __shared__ _Float16 ts[32*32];
  __shared__ float b1s[1024];
  int bidl=blockIdx.x;
  int bid=(bidl&7)*132+(bidl>>3);
  int v=bid>>2, hq=bid&3;
  int nt=meta[24];
  if(v>=nt) return;
  int e=meta[32+v], row0=meta[32+MAXT+v];
  int er=e*2+rb;
  const _Float16* w1b=w1t+(size_t)er*524288 + (size_t)hq*32*4096;
  const _Float16* w2b=w2t+(size_t)er*524288 + (size_t)hq*32*4096;
  const float* b1g=b1all+(size_t)er*4096 + hq*1024;
  int tid=threadIdx.x, l=tid&63, w=tid>>6;
  int lm=l&15, lq=l>>4;
  int s16=(w&1)*16, jh=w>>1;
  int arow=s16+lm;

  for(int g=tid; g<512; g+=256){
    int row=g>>4, slot=g&15;
    const float* src=zin+(size_t)(row0+row)*128+slot*8;
    float4 v0=*(const float4*)src;
    float4 v1=*(const float4*)(src+4);
    f16x8 hv;
    hv[0]=(_Float16)fmaxf(v0.x,0.f); hv[1]=(_Float16)fmaxf(v0.y,0.f);
    hv[2]=(_Float16)fmaxf(v0.z,0.f); hv[3]=(_Float16)fmaxf(v0.w,0.f);
    hv[4]=(_Float16)fmaxf(v1.x,0.f); hv[5]=(_Float16)fmaxf(v1.y,0.f);
    hv[6]=(_Float16)fmaxf(v1.z,0.f); hv[7]=(_Float16)fmaxf(v1.w,0.f);
    *(f16x8*)(&zh[(row*128+slot*8)^((row&7)<<3)])=hv;
  }
  for(int g=tid; g<1024; g+=256) b1s[g]=b1g[g];

  #pragma unroll
  for(int s=0;s<2;++s){
    int so=(w*2+s)*512;
    GLL16(w1b+so+l*8, &wb[0][so]);
    GLL16(w2b+so+l*8, &wb[0][4096+so]);
  }
  asm volatile("s_waitcnt lgkmcnt(0)" ::: "memory");
  __builtin_amdgcn_sched_barrier(0);
  __builtin_amdgcn_s_barrier();

  f32x4 yacc[4];
  #pragma unroll
  for(int i=0;i<4;++i){ yacc[i][0]=0.f; yacc[i][1]=0.f; yacc[i][2]=0.f; yacc[i][3]=0.f; }

  for(int cc=0; cc<32; ++cc){
    int buf=cc&1;
    if(cc<31){
      const _Float16* g1=w1b+(size_t)(cc+1)*4096;
      const _Float16* g2=w2b+(size_t)(cc+1)*4096;
      int nb=buf^1;
      #pragma unroll
      for(int s=0;s<2;++s){
        int so=(w*2+s)*512;
        GLL16(g1+so+l*8, &wb[nb][so]);
        GLL16(g2+so+l*8, &wb[nb][4096+so]);
      }
      asm volatile("s_waitcnt vmcnt(4)" ::: "memory");
    }else{
      asm volatile("s_waitcnt vmcnt(0)" ::: "memory");
    }
    __builtin_amdgcn_sched_barrier(0);
    __builtin_amdgcn_s_barrier();

    f32x4 tacc={0.f,0.f,0.f,0.f};
    int j=jh*16+lm;
    #pragma unroll
    for(int ks=0;ks<4;++ks){
      f16x8 a=*(const f16x8*)(&zh[(arow*128+ks*32+lq*8)^((arow&7)<<3)]);
      f16x8 b=*(const f16x8*)(&wb[buf][(j*128+ks*32+lq*8)^((j&7)<<3)]);
      tacc=__builtin_amdgcn_mfma_f32_16x16x32_f16(a,b,tacc,0,0,0);
    }
    float b1v=b1s[cc*32+j];
    #pragma unroll
    for(int r=0;r<4;++r){
      int trow=s16+lq*4+r;
      ts[(trow*32+j)^((trow&7)<<3)]=(_Float16)fmaxf(tacc[r]+b1v,0.f);
    }
    asm volatile("s_waitcnt lgkmcnt(0)" ::: "memory");
    __builtin_amdgcn_sched_barrier(0);
    __builtin_amdgcn_s_barrier();

    f16x8 a2=*(const f16x8*)(&ts[(arow*32+lq*8)^((arow&7)<<3)]);
    #pragma unroll
    for(int nf=0;nf<4;++nf){
      int n=jh*64+nf*16+lm;
      f16x8 b=*(const f16x8*)(&wb[buf][4096+((n*32+lq*8)^((n&7)<<3))]);
      yacc[nf]=__builtin_amdgcn_mfma_f32_16x16x32_f16(a2,b,yacc[nf],0,0,0);
    }
    __builtin_amdgcn_s_barrier();
  }

  float* yp=ypart+(size_t)hq*CAPR*128;
  #pragma unroll
  for(int nf=0;nf<4;++nf){
    int col=jh*64+nf*16+lm;
    #pragma unroll
    for(int r=0;r<4;++r)
      yp[(size_t)(row0+s16+lq*4+r)*128+col]=yacc[nf][r];
  }
}

// combine 4 hid-quadrant partials + gated residual; rb==1 fuses head dot + ordered scatter
__global__ __launch_bounds__(256) void k_comb(const float* __restrict__ zin, const float* __restrict__ ypart,
    const float* __restrict__ b2all, const float* __restrict__ gates, const int* __restrict__ meta,
    int rb, float* __restrict__ zout,
    const float* __restrict__ hWg, const float* __restrict__ hbg, const int* __restrict__ islot,
    float* __restrict__ out)
{
  int v=blockIdx.x;
  if(v>=meta[24]) return;
  int e=meta[32+v], row0=meta[32+MAXT+v];
  int er=e*2+rb;
  float ge=sigm(gates[er]);
  const float* b2=b2all+(size_t)er*128;
  int tid=threadIdx.x;
  const size_t HS=(size_t)CAPR*128;
  if(rb==0){
    for(int idx=tid; idx<32*128; idx+=256){
      int r=idx>>7, c=idx&127;
      size_t o=(size_t)(row0+r)*128+c;
      float y=ypart[o]+ypart[HS+o]+ypart[2*HS+o]+ypart[3*HS+o];
      float zr=fmaxf(zin[o],0.f);
      zout[o]=ge*(y+b2[c])+(1.f-ge)*zr;
    }
  }else{
    int r=tid>>3, cs=tid&7;
    float acc=0.f;
    size_t ro=(size_t)(row0+r)*128;
    #pragma unroll
    for(int q=0;q<16;++q){
      int c=cs*16+q;
      size_t o=ro+c;
      float y=ypart[o]+ypart[HS+o]+ypart[2*HS+o]+ypart[3*HS+o];
      float zr=fmaxf(zin[o],0.f);
      float zf=ge*(y+b2[c])+(1.f-ge)*zr;
      acc+=zf*hWg[e*128+c];
    }
    acc+=__shfl_xor(acc,1); acc+=__shfl_xor(acc,2); acc+=__shfl_xor(acc,4);
    if(cs==0){
      int pos=islot[row0+r];
      if(pos>=0) out[pos]=acc+hbg[e];
    }
  }
}

extern "C" void kernel_launch(void* const* d_in, const int* in_sizes, int n_in,
                              void* d_out, int out_size, void* d_ws, size_t ws_size,
                              hipStream_t stream){
  const float* x     =(const float*)d_in[0];
  const int*   ei    =(const int*)  d_in[1];
  const float* ea    =(const float*)d_in[2];
  const int*   ecross=(const int*)  d_in[3];
  const int*   types =(const int*)  d_in[4];
  const float* gWl   =(const float*)d_in[5];
  const float* gbl   =(const float*)d_in[6];
  const float* gWr   =(const float*)d_in[7];
  const float* gbr   =(const float*)d_in[8];
  const float* gWe   =(const float*)d_in[9];
  const float* gatt  =(const float*)d_in[10];
  const float* gbias =(const float*)d_in[11];
  const float* ggate =(const float*)d_in[12];
  const float* rW1   =(const float*)d_in[13];
  const float* rb1   =(const float*)d_in[14];
  const float* rW2   =(const float*)d_in[15];
  const float* rb2   =(const float*)d_in[16];
  const float* rg    =(const float*)d_in[17];
  const float* hW    =(const float*)d_in[18];
  const float* hb    =(const float*)d_in[19];
  float* out=(float*)d_out;

  char* base=(char*)d_ws;
  size_t off=0;
  auto alloc=[&](size_t bytes)->char*{
    char* p=base+off;
    off=(off+bytes+511)&~((size_t)511);
    return p;
  };
  float* hA     =(float*)alloc((size_t)NN*64*4);
  float* hB     =(float*)alloc((size_t)NN*64*4);   // reused as zB in expert phase
  int*   deg    =(int*)  alloc((size_t)NN*4);
  int*   row_ptr=(int*)  alloc((size_t)(NN+1)*4);
  int*   cursor =(int*)  alloc((size_t)NN*4);
  int*   csr_src=(int*)  alloc((size_t)(NE+16)*4);
  int*   meta   =(int*)  alloc(1024*4);
  int*   slotp  =(int*)  alloc((size_t)NP*4);
  int*   islot  =(int*)  alloc((size_t)CAPR*4);
  float* zA     =(float*)alloc((size_t)CAPR*128*4);
  // union region: {xl, xr, eas} (GAT) overlaid with {w1t, w2t, ypart} (experts)
  size_t uoff=off;
  float* xl =(float*)(base+uoff);
  float* xr =(float*)(base+uoff+(size_t)NN*256*4);
  float* eas=(float*)(base+uoff+(size_t)NN*256*4*2);
  _Float16* w1t=(_Float16*)(base+uoff);
  _Float16* w2t=(_Float16*)(base+uoff+(size_t)16*524288*2);
  float* ypart =(float*)(base+uoff+(size_t)16*524288*2*2);
  size_t gat_bytes=(size_t)NN*256*4*2 + (size_t)(NE*12+16)*4;
  size_t exp_bytes=(size_t)16*524288*2*2 + (size_t)4*CAPR*128*4;
  size_t need=uoff+(gat_bytes>exp_bytes?gat_bytes:exp_bytes);
  if(ws_size<need) return;
  float* zB=hB;

  // ---- CSR by target (+src/ea materialization) + pair sort ----
  k_fill_i<<<(NN+255)/256,256,0,stream>>>(deg,NN,0);
  k_deg<<<(NE+255)/256,256,0,stream>>>(ei,deg);
  k_scan<<<1,1024,0,stream>>>(deg,row_ptr,cursor);
  k_fill_csr2<<<(NE+255)/256,256,0,stream>>>(ei,ea,cursor,csr_src,eas);
  k_sort<<<1,256,0,stream>>>(types,meta,slotp,islot);

  // ---- GAT layers ----
  const float* hcur=x;
  float* hnext=hA;
  for(int L=0;L<NL;++L){
    k_nodexf<<<(NN+63)/64,256,0,stream>>>(hcur, gWl+(size_t)L*64*256, gbl+(size_t)L*256,
                                          gWr+(size_t)L*64*256, gbr+(size_t)L*256, xl, xr, L>0?1:0);
    k_agg4<<<NN/4,256,0,stream>>>(xl,xr,eas,csr_src,row_ptr, gWe+(size_t)L*EDIM*256,
                                  gatt+(size_t)L*256, gbias+(size_t)L*64, ggate, L, hcur, hnext);
    hcur=hnext;
    hnext=(hcur==hA)?hB:hA;
  }
  // hcur == hA after 3 layers; hB is dead -> zB overlay is safe

  // ---- pair gather into type-sorted padded layout ----
  k_buildz<<<NP*64/256,256,0,stream>>>(hcur,ecross,slotp,zA);

  // ---- weight prep: fp16, chunked, transposed, swizzle baked in (xl/xr/eas now dead) ----
  k_prepw1<<<2048,256,0,stream>>>(rW1,w1t);
  k_prepw2<<<2048,256,0,stream>>>(rW2,w2t);

  // ---- routed experts: 2 res-blocks, each = MFMA partial + combine ----
  k_resmfma<<<1056,256,0,stream>>>(zA,w1t,w2t,rb1,meta,ypart,0);
  k_comb<<<MAXT,256,0,stream>>>(zA,ypart,rb2,rg,meta,0,zB,hW,hb,islot,out);
  k_resmfma<<<1056,256,0,stream>>>(zB,w1t,w2t,rb1,meta,ypart,1);
  k_comb<<<MAXT,256,0,stream>>>(zB,ypart,rb2,rg,meta,1,zA,hW,hb,islot,out);

  (void)in_sizes; (void)n_in; (void)out_size;
}

// Round 11
// 582.039 us; speedup vs baseline: 1.2552x; 1.2552x over previous
//
#include <hip/hip_runtime.h>

#define NN 20000
#define NE 320000
#define NL 3
#define NP 8192
#define EDIM 9
#define TROWS 32
#define MAXT 272
#define CAPR (MAXT*TROWS)

typedef _Float16 f16x8 __attribute__((ext_vector_type(8)));
typedef float f32x4 __attribute__((ext_vector_type(4)));

#define GLL16(g,l) __builtin_amdgcn_global_load_lds((const __attribute__((address_space(1))) unsigned int*)(g), (__attribute__((address_space(3))) unsigned int*)(l), 16, 0, 0)

__device__ __forceinline__ float sigm(float x){ return 1.f/(1.f+__expf(-x)); }

// wave64 sum via DPP through compiler intrinsics (hazard-safe; round-7 proven)
__device__ __forceinline__ float dpp_sum64(float x){
  x += __int_as_float(__builtin_amdgcn_update_dpp(0, __float_as_int(x), 0x111, 0xf, 0xf, true));
  x += __int_as_float(__builtin_amdgcn_update_dpp(0, __float_as_int(x), 0x112, 0xf, 0xf, true));
  x += __int_as_float(__builtin_amdgcn_update_dpp(0, __float_as_int(x), 0x114, 0xf, 0xf, true));
  x += __int_as_float(__builtin_amdgcn_update_dpp(0, __float_as_int(x), 0x118, 0xf, 0xf, true));
  x += __int_as_float(__builtin_amdgcn_update_dpp(0, __float_as_int(x), 0x142, 0xf, 0xf, true));
  x += __int_as_float(__builtin_amdgcn_update_dpp(0, __float_as_int(x), 0x143, 0xf, 0xf, true));
  return __uint_as_float(__builtin_amdgcn_readlane(__float_as_uint(x), 63));
}

__global__ void k_fill_i(int* __restrict__ p, int n, int v){ int i=blockIdx.x*blockDim.x+threadIdx.x; if(i<n)p[i]=v; }

__global__ void k_deg(const int* __restrict__ ei, int* __restrict__ deg){
  int e=blockIdx.x*blockDim.x+threadIdx.x; if(e<NE) atomicAdd(&deg[ei[NE+e]],1);
}

__global__ __launch_bounds__(1024) void k_scan(const int* __restrict__ deg, int* __restrict__ row_ptr, int* __restrict__ cursor){
  __shared__ int sh[1024];
  __shared__ int carry;
  int tid=threadIdx.x;
  if(tid==0) carry=0;
  __syncthreads();
  for(int base=0;base<NN;base+=1024){
    int i=base+tid;
    int v=(i<NN)?deg[i]:0;
    sh[tid]=v; __syncthreads();
    for(int o=1;o<1024;o<<=1){
      int t=(tid>=o)?sh[tid-o]:0; __syncthreads();
      sh[tid]+=t; __syncthreads();
    }
    int incl=sh[tid];
    int c=carry;
    if(i<NN){ row_ptr[i+1]=c+incl; cursor[i]=c+incl-v; }
    if(i==0) row_ptr[0]=0;
    __syncthreads();
    if(tid==1023) carry=c+incl;
    __syncthreads();
  }
}

// CSR fill with source-node + edge-attr materialized in slot order
__global__ void k_fill_csr2(const int* __restrict__ ei, const float* __restrict__ ea,
    int* __restrict__ cursor, int* __restrict__ csr_src, float* __restrict__ eas){
  int e=blockIdx.x*blockDim.x+threadIdx.x;
  if(e<NE){
    int t=ei[NE+e]; int pos=atomicAdd(&cursor[t],1);
    csr_src[pos]=ei[e];
    const float* s=ea+(size_t)e*9;
    float* d=eas+(size_t)pos*12;
    #pragma unroll
    for(int k=0;k<9;++k) d[k]=s[k];
    d[9]=0.f; d[10]=0.f; d[11]=0.f;
  }
}

// stable counting-sort of pairs by type; tiles of 32 rows padded per group; islot = slot->output pos
__global__ __launch_bounds__(256) void k_sort(const int* __restrict__ types, int* __restrict__ meta,
    int* __restrict__ slotp, int* __restrict__ islot){
  __shared__ int cnt[256][8];
  __shared__ int tot[8];
  __shared__ int base_s[8], pad_s[8];
  int tid=threadIdx.x;
  int lc[8]={0,0,0,0,0,0,0,0};
  int tl[32];
  for(int i=0;i<32;++i){ int ty=types[tid*32+i]; tl[i]=ty; lc[ty]++; }
  #pragma unroll
  for(int t=0;t<8;++t) cnt[tid][t]=lc[t];
  __syncthreads();
  if(tid<8){
    int run=0;
    for(int j=0;j<256;++j){ int v=cnt[j][tid]; cnt[j][tid]=run; run+=v; }
    tot[tid]=run;
  }
  __syncthreads();
  if(tid==0){
    int b=0, pb=0, nt=0;
    for(int t=0;t<8;++t){
      base_s[t]=b; pad_s[t]=pb;
      meta[t]=tot[t]; meta[8+t]=b; meta[16+t]=pb;
      int ntt=(tot[t]+31)>>5;
      for(int j=0;j<ntt;++j){ meta[32+nt]=t; meta[32+MAXT+nt]=pb+j*32; nt++; }
      b+=tot[t]; pb+=ntt*32;
    }
    meta[24]=nt; meta[25]=pb;
  }
  __syncthreads();
  if(tid<8){
    int t=tid; int ntt=(tot[t]+31)>>5;
    for(int sr=tot[t]; sr<ntt*32; ++sr) islot[pad_s[t]+sr]=-1;
  }
  int run[8];
  #pragma unroll
  for(int t=0;t<8;++t) run[t]=cnt[tid][t];
  for(int i=0;i<32;++i){
    int p=tid*32+i; int t=tl[i]; int r=run[t]++;
    int pos=base_s[t]+r, slot=pad_s[t]+r;
    slotp[p]=slot; islot[slot]=pos;
  }
}

// node transform v2: grid 313x8, each block = (64-node tile) x (one 64-col chunk of xl|xr).
// hsT[k][r] transposed staging -> both MACC operands read as ds_read_b128.
__global__ __launch_bounds__(256) void k_nodexf(const float* __restrict__ hin,
    const float* __restrict__ Wl, const float* __restrict__ bl,
    const float* __restrict__ Wr, const float* __restrict__ br,
    float* __restrict__ xl, float* __restrict__ xr, int lk){
  __shared__ float hsT[64][68];   // [k][r], stride 68 floats = 272B (16B-aligned rows)
  __shared__ float ws[64][68];    // [k][j]
  int bid=blockIdx.x;
  int n0=(bid>>3)*64, ch=bid&7;
  const float* W=(ch<4)?Wl:Wr;
  const float* bb=(ch<4)?bl:br;
  float* outp=(ch<4)?xl:xr;
  int c0=(ch&3)*64;
  int tid=threadIdx.x;

  // stage hsT (transposed, leaky applied): thread handles (r, 4k-group)
  for(int idx=tid; idx<64*16; idx+=256){
    int r=idx&63, kq=idx>>6;
    int n=n0+r;
    float4 v=make_float4(0.f,0.f,0.f,0.f);
    if(n<NN) v=*(const float4*)&hin[(size_t)n*64+kq*4];
    if(lk){
      v.x=v.x>0.f?v.x:0.01f*v.x; v.y=v.y>0.f?v.y:0.01f*v.y;
      v.z=v.z>0.f?v.z:0.01f*v.z; v.w=v.w>0.f?v.w:0.01f*v.w;
    }
    hsT[kq*4+0][r]=v.x; hsT[kq*4+1][r]=v.y; hsT[kq*4+2][r]=v.z; hsT[kq*4+3][r]=v.w;
  }
  // stage ws chunk (64 k x 64 j), float4
  for(int idx=tid; idx<64*16; idx+=256){
    int k=idx>>4, j4=idx&15;
    *(float4*)&ws[k][j4*4]=*(const float4*)&W[(size_t)k*256+c0+j4*4];
  }
  __syncthreads();

  int ty=tid>>4, tx=tid&15;
  float acc[4][4]={};
  #pragma unroll 4
  for(int k=0;k<64;++k){
    float4 a=*(const float4*)&hsT[k][4*ty];
    float4 b=*(const float4*)&ws[k][4*tx];
    float aa[4]={a.x,a.y,a.z,a.w}, bbv[4]={b.x,b.y,b.z,b.w};
    #pragma unroll
    for(int i=0;i<4;++i){
      #pragma unroll
      for(int j=0;j<4;++j) acc[i][j]=fmaf(aa[i],bbv[j],acc[i][j]);
    }
  }
  float4 bias4=*(const float4*)&bb[c0+4*tx];
  #pragma unroll
  for(int i=0;i<4;++i){
    int n=n0+4*ty+i;
    if(n<NN){
      float4 o=make_float4(acc[i][0]+bias4.x, acc[i][1]+bias4.y, acc[i][2]+bias4.z, acc[i][3]+bias4.w);
      *(float4*)&outp[(size_t)n*256+c0+4*tx]=o;
    }
  }
}

// fused GAT edge pipeline (round-7 proven): sequential csr_src/eas streams +
// depth-4 rolling xl prefetch + DPP wave-sum
__global__ __launch_bounds__(256) void k_agg2(const float* __restrict__ xl, const float* __restrict__ xr,
    const float* __restrict__ eas, const int* __restrict__ csr_src, const int* __restrict__ row_ptr,
    const float* __restrict__ WeL, const float* __restrict__ attL,
    const float* __restrict__ biasL, const float* __restrict__ gates, int layer,
    const float* __restrict__ hprev, float* __restrict__ hout){
  __shared__ float red[4][64];
  int n=blockIdx.x, tid=threadIdx.x;
  float w0=WeL[tid],      w1=WeL[256+tid],  w2=WeL[512+tid],  w3=WeL[768+tid],  w4=WeL[1024+tid];
  float w5=WeL[1280+tid], w6=WeL[1536+tid], w7=WeL[1792+tid], w8=WeL[2048+tid];
  float att_t=attL[tid];
  float xr_t=xr[(size_t)n*256+tid];
  int s=row_ptr[n], t=row_ptr[n+1];
  float den=0.f, acc=0.f;

  auto body=[&](float xlv, int j){
    const float4* ep=(const float4*)(eas+(size_t)j*12);
    float4 e0=ep[0], e1=ep[1];
    float e8=eas[(size_t)j*12+8];
    float ev=e0.x*w0+e0.y*w1+e0.z*w2+e0.w*w3+e1.x*w4+e1.y*w5+e1.z*w6+e1.w*w7+e8*w8;
    float m=xlv+xr_t+ev;
    m=m>0.f?m:0.2f*m;
    float pt=dpp_sum64(m*att_t);
    float a=__expf(pt);
    den+=a; acc+=a*xlv;
  };

  float x0=0.f,x1=0.f,x2=0.f,x3=0.f;
  if(s+0<t) x0=xl[(size_t)csr_src[s+0]*256+tid];
  if(s+1<t) x1=xl[(size_t)csr_src[s+1]*256+tid];
  if(s+2<t) x2=xl[(size_t)csr_src[s+2]*256+tid];
  if(s+3<t) x3=xl[(size_t)csr_src[s+3]*256+tid];
  int j=s;
  while(j+7<t){
    float y0=xl[(size_t)csr_src[j+4]*256+tid];
    float y1=xl[(size_t)csr_src[j+5]*256+tid];
    float y2=xl[(size_t)csr_src[j+6]*256+tid];
    float y3=xl[(size_t)csr_src[j+7]*256+tid];
    body(x0,j); body(x1,j+1); body(x2,j+2); body(x3,j+3);
    x0=y0; x1=y1; x2=y2; x3=y3;
    j+=4;
  }
  if(j<t){ body(x0,j); ++j; }
  if(j<t){ body(x1,j); ++j; }
  if(j<t){ body(x2,j); ++j; }
  if(j<t){ body(x3,j); ++j; }
  while(j<t){ body(xl[(size_t)csr_src[j]*256+tid], j); ++j; }

  float rdn=den>0.f?1.f/den:0.f;
  int h=tid>>6, cc=tid&63;
  red[h][cc]=acc*rdn;
  __syncthreads();
  if(tid<64){
    float mean=(red[0][tid]+red[1][tid]+red[2][tid]+red[3][tid])*0.25f + biasL[tid];
    float o;
    if(layer==0) o=mean;
    else{
      float hp=hprev[(size_t)n*64+tid];
      hp=hp>0.f?hp:0.01f*hp;
      float g=sigm(gates[layer-1]);
      o=g*mean+(1.f-g)*hp;
    }
    hout[(size_t)n*64+tid]=o;
  }
}

// z0[slot, 2c]=h[a,c], z0[slot,2c+1]=h[b,c]
__global__ void k_buildz(const float* __restrict__ hfin, const int* __restrict__ ecross,
    const int* __restrict__ slotp, float* __restrict__ z){
  int g=blockIdx.x*blockDim.x+threadIdx.x;
  if(g>=NP*64) return;
  int p=g>>6, c=g&63;
  int a=ecross[2*p], b=ecross[2*p+1];
  int slot=slotp[p];
  float2 v; v.x=hfin[(size_t)a*64+c]; v.y=hfin[(size_t)b*64+c];
  ((float2*)(z+(size_t)slot*128))[c]=v;
}

// W1 prep: per (er, chunk of 32 j): chunk-linear fp16 image [jl(32)][k(128)] with
// XOR swizzle ((jl*128+k) ^ ((jl&7)<<3)) baked in -> global_load_lds drops it verbatim.
__global__ __launch_bounds__(256) void k_prepw1(const float* __restrict__ src, _Float16* __restrict__ dst){
  __shared__ float lds[128][33];
  int bid=blockIdx.x, er=bid>>7, ch=bid&127;
  const float* s=src+(size_t)er*128*4096 + ch*32;
  int tid=threadIdx.x;
  for(int idx=tid; idx<128*32; idx+=256){ int k=idx>>5, jl=idx&31; lds[k][jl]=s[(size_t)k*4096+jl]; }
  __syncthreads();
  _Float16* d=dst+(size_t)bid*4096;
  for(int g=tid; g<512; g+=256){
    int jl=g>>4, k8=g&15;
    f16x8 v;
    #pragma unroll
    for(int t=0;t<8;++t) v[t]=(_Float16)lds[k8*8+t][jl];
    int elem=(jl*128+k8*8)^((jl&7)<<3);
    *(f16x8*)(&d[elem])=v;
  }
}

// W2 prep: per (er, chunk of 32 j): [n(128)][jl(32)] with XOR swizzle ((n*32+jl) ^ ((n&7)<<3)).
__global__ __launch_bounds__(256) void k_prepw2(const float* __restrict__ src, _Float16* __restrict__ dst){
  __shared__ float lds[32][130];
  int bid=blockIdx.x, er=bid>>7, ch=bid&127;
  const float* s=src+(size_t)er*4096*128 + (size_t)ch*32*128;
  int tid=threadIdx.x;
  for(int idx=tid; idx<32*128; idx+=256){ int j=idx>>7, n=idx&127; lds[j][n]=s[(size_t)j*128+n]; }
  __syncthreads();
  _Float16* d=dst+(size_t)bid*4096;
  for(int g=tid; g<512; g+=256){
    int n=g>>2, j8=g&3;
    f16x8 v;
    #pragma unroll
    for(int t=0;t<8;++t) v[t]=(_Float16)lds[j8*8+t][n];
    int elem=(n*32+j8*8)^((n&7)<<3);
    *(f16x8*)(&d[elem])=v;
  }
}

// MFMA res-block partial: ypart[hq] = relu(relu(z)@W1[:,hq-range]+b1) @ W2[hq-range,:]
__global__ __launch_bounds__(256) void k_resmfma(const float* __restrict__ zin,
    const _Float16* __restrict__ w1t, const _Float16* __restrict__ w2t,
    const float* __restrict__ b1all, const int* __restrict__ meta,
    float* __restrict__ ypart, int rb)
{
  __shared__ _Float16 zh[32*128];
  __shared__ _Float16 wb[2][8192];
  __shared__ _Float16 ts[32*32];
  __shared__ float b1s[1024];
  int bidl=blockIdx.x;
  int bid=(bidl&7)*132+(bidl>>3);
  int v=bid>>2, hq=bid&3;
  int nt=meta[24];
  if(v>=nt) return;
  int e=meta[32+v], row0=meta[32+MAXT+v];
  int er=e*2+rb;
  const _Float16* w1b=w1t+(size_t)er*524288 + (size_t)hq*32*4096;
  const _Float16* w2b=w2t+(size_t)er*524288 + (size_t)hq*32*4096;
  const float* b1g=b1all+(size_t)er*4096 + hq*1024;
  int tid=threadIdx.x, l=tid&63, w=tid>>6;
  int lm=l&15, lq=l>>4;
  int s16=(w&1)*16, jh=w>>1;
  int arow=s16+lm;

  for(int g=tid; g<512; g+=256){
    int row=g>>4, slot=g&15;
    const float* src=zin+(size_t)(row0+row)*128+slot*8;
    float4 v0=*(const float4*)src;
    float4 v1=*(const float4*)(src+4);
    f16x8 hv;
    hv[0]=(_Float16)fmaxf(v0.x,0.f); hv[1]=(_Float16)fmaxf(v0.y,0.f);
    hv[2]=(_Float16)fmaxf(v0.z,0.f); hv[3]=(_Float16)fmaxf(v0.w,0.f);
    hv[4]=(_Float16)fmaxf(v1.x,0.f); hv[5]=(_Float16)fmaxf(v1.y,0.f);
    hv[6]=(_Float16)fmaxf(v1.z,0.f); hv[7]=(_Float16)fmaxf(v1.w,0.f);
    *(f16x8*)(&zh[(row*128+slot*8)^((row&7)<<3)])=hv;
  }
  for(int g=tid; g<1024; g+=256) b1s[g]=b1g[g];

  #pragma unroll
  for(int s=0;s<2;++s){
    int so=(w*2+s)*512;
    GLL16(w1b+so+l*8, &wb[0][so]);
    GLL16(w2b+so+l*8, &wb[0][4096+so]);
  }
  asm volatile("s_waitcnt lgkmcnt(0)" ::: "memory");
  __builtin_amdgcn_sched_barrier(0);
  __builtin_amdgcn_s_barrier();

  f32x4 yacc[4];
  #pragma unroll
  for(int i=0;i<4;++i){ yacc[i][0]=0.f; yacc[i][1]=0.f; yacc[i][2]=0.f; yacc[i][3]=0.f; }

  for(int cc=0; cc<32; ++cc){
    int buf=cc&1;
    if(cc<31){
      const _Float16* g1=w1b+(size_t)(cc+1)*4096;
      const _Float16* g2=w2b+(size_t)(cc+1)*4096;
      int nb=buf^1;
      #pragma unroll
      for(int s=0;s<2;++s){
        int so=(w*2+s)*512;
        GLL16(g1+so+l*8, &wb[nb][so]);
        GLL16(g2+so+l*8, &wb[nb][4096+so]);
      }
      asm volatile("s_waitcnt vmcnt(4)" ::: "memory");
    }else{
      asm volatile("s_waitcnt vmcnt(0)" ::: "memory");
    }
    __builtin_amdgcn_sched_barrier(0);
    __builtin_amdgcn_s_barrier();

    f32x4 tacc={0.f,0.f,0.f,0.f};
    int j=jh*16+lm;
    #pragma unroll
    for(int ks=0;ks<4;++ks){
      f16x8 a=*(const f16x8*)(&zh[(arow*128+ks*32+lq*8)^((arow&7)<<3)]);
      f16x8 b=*(const f16x8*)(&wb[buf][(j*128+ks*32+lq*8)^((j&7)<<3)]);
      tacc=__builtin_amdgcn_mfma_f32_16x16x32_f16(a,b,tacc,0,0,0);
    }
    float b1v=b1s[cc*32+j];
    #pragma unroll
    for(int r=0;r<4;++r){
      int trow=s16+lq*4+r;
      ts[(trow*32+j)^((trow&7)<<3)]=(_Float16)fmaxf(tacc[r]+b1v,0.f);
    }
    asm volatile("s_waitcnt lgkmcnt(0)" ::: "memory");
    __builtin_amdgcn_sched_barrier(0);
    __builtin_amdgcn_s_barrier();

    f16x8 a2=*(const f16x8*)(&ts[(arow*32+lq*8)^((arow&7)<<3)]);
    #pragma unroll
    for(int nf=0;nf<4;++nf){
      int n=jh*64+nf*16+lm;
      f16x8 b=*(const f16x8*)(&wb[buf][4096+((n*32+lq*8)^((n&7)<<3))]);
      yacc[nf]=__builtin_amdgcn_mfma_f32_16x16x32_f16(a2,b,yacc[nf],0,0,0);
    }
    __builtin_amdgcn_s_barrier();
  }

  float* yp=ypart+(size_t)hq*CAPR*128;
  #pragma unroll
  for(int nf=0;nf<4;++nf){
    int col=jh*64+nf*16+lm;
    #pragma unroll
    for(int r=0;r<4;++r)
      yp[(size_t)(row0+s16+lq*4+r)*128+col]=yacc[nf][r];
  }
}

// combine 4 hid-quadrant partials + gated residual; rb==1 fuses head dot + ordered scatter
__global__ __launch_bounds__(256) void k_comb(const float* __restrict__ zin, const float* __restrict__ ypart,
    const float* __restrict__ b2all, const float* __restrict__ gates, const int* __restrict__ meta,
    int rb, float* __restrict__ zout,
    const float* __restrict__ hWg, const float* __restrict__ hbg, const int* __restrict__ islot,
    float* __restrict__ out)
{
  int v=blockIdx.x;
  if(v>=meta[24]) return;
  int e=meta[32+v], row0=meta[32+MAXT+v];
  int er=e*2+rb;
  float ge=sigm(gates[er]);
  const float* b2=b2all+(size_t)er*128;
  int tid=threadIdx.x;
  const size_t HS=(size_t)CAPR*128;
  if(rb==0){
    for(int idx=tid; idx<32*128; idx+=256){
      int r=idx>>7, c=idx&127;
      size_t o=(size_t)(row0+r)*128+c;
      float y=ypart[o]+ypart[HS+o]+ypart[2*HS+o]+ypart[3*HS+o];
      float zr=fmaxf(zin[o],0.f);
      zout[o]=ge*(y+b2[c])+(1.f-ge)*zr;
    }
  }else{
    int r=tid>>3, cs=tid&7;
    float acc=0.f;
    size_t ro=(size_t)(row0+r)*128;
    #pragma unroll
    for(int q=0;q<16;++q){
      int c=cs*16+q;
      size_t o=ro+c;
      float y=ypart[o]+ypart[HS+o]+ypart[2*HS+o]+ypart[3*HS+o];
      float zr=fmaxf(zin[o],0.f);
      float zf=ge*(y+b2[c])+(1.f-ge)*zr;
      acc+=zf*hWg[e*128+c];
    }
    acc+=__shfl_xor(acc,1); acc+=__shfl_xor(acc,2); acc+=__shfl_xor(acc,4);
    if(cs==0){
      int pos=islot[row0+r];
      if(pos>=0) out[pos]=acc+hbg[e];
    }
  }
}

extern "C" void kernel_launch(void* const* d_in, const int* in_sizes, int n_in,
                              void* d_out, int out_size, void* d_ws, size_t ws_size,
                              hipStream_t stream){
  const float* x     =(const float*)d_in[0];
  const int*   ei    =(const int*)  d_in[1];
  const float* ea    =(const float*)d_in[2];
  const int*   ecross=(const int*)  d_in[3];
  const int*   types =(const int*)  d_in[4];
  const float* gWl   =(const float*)d_in[5];
  const float* gbl   =(const float*)d_in[6];
  const float* gWr   =(const float*)d_in[7];
  const float* gbr   =(const float*)d_in[8];
  const float* gWe   =(const float*)d_in[9];
  const float* gatt  =(const float*)d_in[10];
  const float* gbias =(const float*)d_in[11];
  const float* ggate =(const float*)d_in[12];
  const float* rW1   =(const float*)d_in[13];
  const float* rb1   =(const float*)d_in[14];
  const float* rW2   =(const float*)d_in[15];
  const float* rb2   =(const float*)d_in[16];
  const float* rg    =(const float*)d_in[17];
  const float* hW    =(const float*)d_in[18];
  const float* hb    =(const float*)d_in[19];
  float* out=(float*)d_out;

  char* base=(char*)d_ws;
  size_t off=0;
  auto alloc=[&](size_t bytes)->char*{
    char* p=base+off;
    off=(off+bytes+511)&~((size_t)511);
    return p;
  };
  float* hA     =(float*)alloc((size_t)NN*64*4);
  float* hB     =(float*)alloc((size_t)NN*64*4);   // reused as zB in expert phase
  int*   deg    =(int*)  alloc((size_t)NN*4);
  int*   row_ptr=(int*)  alloc((size_t)(NN+1)*4);
  int*   cursor =(int*)  alloc((size_t)NN*4);
  int*   csr_src=(int*)  alloc((size_t)(NE+16)*4);
  int*   meta   =(int*)  alloc(1024*4);
  int*   slotp  =(int*)  alloc((size_t)NP*4);
  int*   islot  =(int*)  alloc((size_t)CAPR*4);
  float* zA     =(float*)alloc((size_t)CAPR*128*4);
  // union region: {xl, xr, eas} (GAT) overlaid with {w1t, w2t, ypart} (experts)
  size_t uoff=off;
  float* xl =(float*)(base+uoff);
  float* xr =(float*)(base+uoff+(size_t)NN*256*4);
  float* eas=(float*)(base+uoff+(size_t)NN*256*4*2);
  _Float16* w1t=(_Float16*)(base+uoff);
  _Float16* w2t=(_Float16*)(base+uoff+(size_t)16*524288*2);
  float* ypart =(float*)(base+uoff+(size_t)16*524288*2*2);
  size_t gat_bytes=(size_t)NN*256*4*2 + (size_t)(NE*12+16)*4;
  size_t exp_bytes=(size_t)16*524288*2*2 + (size_t)4*CAPR*128*4;
  size_t need=uoff+(gat_bytes>exp_bytes?gat_bytes:exp_bytes);
  if(ws_size<need) return;
  float* zB=hB;

  // ---- CSR by target (+src/ea materialization) + pair sort ----
  k_fill_i<<<(NN+255)/256,256,0,stream>>>(deg,NN,0);
  k_deg<<<(NE+255)/256,256,0,stream>>>(ei,deg);
  k_scan<<<1,1024,0,stream>>>(deg,row_ptr,cursor);
  k_fill_csr2<<<(NE+255)/256,256,0,stream>>>(ei,ea,cursor,csr_src,eas);
  k_sort<<<1,256,0,stream>>>(types,meta,slotp,islot);

  // ---- GAT layers ----
  const float* hcur=x;
  float* hnext=hA;
  for(int L=0;L<NL;++L){
    k_nodexf<<<((NN+63)/64)*8,256,0,stream>>>(hcur, gWl+(size_t)L*64*256, gbl+(size_t)L*256,
                                              gWr+(size_t)L*64*256, gbr+(size_t)L*256, xl, xr, L>0?1:0);
    k_agg2<<<NN,256,0,stream>>>(xl,xr,eas,csr_src,row_ptr, gWe+(size_t)L*EDIM*256,
                                gatt+(size_t)L*256, gbias+(size_t)L*64, ggate, L, hcur, hnext);
    hcur=hnext;
    hnext=(hcur==hA)?hB:hA;
  }
  // hcur == hA after 3 layers; hB is dead -> zB overlay is safe

  // ---- pair gather into type-sorted padded layout ----
  k_buildz<<<NP*64/256,256,0,stream>>>(hcur,ecross,slotp,zA);

  // ---- weight prep: fp16, chunked, transposed, swizzle baked in (xl/xr/eas now dead) ----
  k_prepw1<<<2048,256,0,stream>>>(rW1,w1t);
  k_prepw2<<<2048,256,0,stream>>>(rW2,w2t);

  // ---- routed experts: 2 res-blocks, each = MFMA partial + combine ----
  k_resmfma<<<1056,256,0,stream>>>(zA,w1t,w2t,rb1,meta,ypart,0);
  k_comb<<<MAXT,256,0,stream>>>(zA,ypart,rb2,rg,meta,0,zB,hW,hb,islot,out);
  k_resmfma<<<1056,256,0,stream>>>(zB,w1t,w2t,rb1,meta,ypart,1);
  k_comb<<<MAXT,256,0,stream>>>(zB,ypart,rb2,rg,meta,1,zA,hW,hb,islot,out);

  (void)in_sizes; (void)n_in; (void)out_size;
}

// Round 12
// 578.586 us; speedup vs baseline: 1.2627x; 1.0060x over previous
//
#include <hip/hip_runtime.h>

#define NN 20000
#define NE 320000
#define NL 3
#define NP 8192
#define EDIM 9
#define TROWS 32
#define MAXT 272
#define CAPR (MAXT*TROWS)
#define NB ((NN+255)/256)

typedef _Float16 f16x8 __attribute__((ext_vector_type(8)));
typedef float f32x4 __attribute__((ext_vector_type(4)));

#define GLL16(g,l) __builtin_amdgcn_global_load_lds((const __attribute__((address_space(1))) unsigned int*)(g), (__attribute__((address_space(3))) unsigned int*)(l), 16, 0, 0)

__device__ __forceinline__ float sigm(float x){ return 1.f/(1.f+__expf(-x)); }

// wave64 sum via DPP through compiler intrinsics (hazard-safe; round-7 proven)
__device__ __forceinline__ float dpp_sum64(float x){
  x += __int_as_float(__builtin_amdgcn_update_dpp(0, __float_as_int(x), 0x111, 0xf, 0xf, true));
  x += __int_as_float(__builtin_amdgcn_update_dpp(0, __float_as_int(x), 0x112, 0xf, 0xf, true));
  x += __int_as_float(__builtin_amdgcn_update_dpp(0, __float_as_int(x), 0x114, 0xf, 0xf, true));
  x += __int_as_float(__builtin_amdgcn_update_dpp(0, __float_as_int(x), 0x118, 0xf, 0xf, true));
  x += __int_as_float(__builtin_amdgcn_update_dpp(0, __float_as_int(x), 0x142, 0xf, 0xf, true));
  x += __int_as_float(__builtin_amdgcn_update_dpp(0, __float_as_int(x), 0x143, 0xf, 0xf, true));
  return __uint_as_float(__builtin_amdgcn_readlane(__float_as_uint(x), 63));
}

__global__ void k_fill_i(int* __restrict__ p, int n, int v){ int i=blockIdx.x*blockDim.x+threadIdx.x; if(i<n)p[i]=v; }

__global__ void k_deg(const int* __restrict__ ei, int* __restrict__ deg){
  int e=blockIdx.x*blockDim.x+threadIdx.x; if(e<NE) atomicAdd(&deg[ei[NE+e]],1);
}

// ---- parallel 3-phase scan (replaces single-block k_scan) ----
__global__ __launch_bounds__(256) void k_scan1(const int* __restrict__ deg, int* __restrict__ incl, int* __restrict__ bsum){
  __shared__ int sh[256];
  int b=blockIdx.x, tid=threadIdx.x;
  int i=b*256+tid;
  int v=(i<NN)?deg[i]:0;
  sh[tid]=v; __syncthreads();
  for(int o=1;o<256;o<<=1){
    int t=(tid>=o)?sh[tid-o]:0; __syncthreads();
    sh[tid]+=t; __syncthreads();
  }
  if(i<NN) incl[i]=sh[tid];
  if(tid==255) bsum[b]=sh[255];
}
__global__ void k_scan2(const int* __restrict__ bsum, int* __restrict__ boff){
  if(blockIdx.x==0 && threadIdx.x==0){
    int run=0;
    for(int b=0;b<NB;++b){ boff[b]=run; run+=bsum[b]; }
  }
}
__global__ void k_scan3(const int* __restrict__ deg, const int* __restrict__ incl,
                        const int* __restrict__ boff, int* __restrict__ row_ptr, int* __restrict__ cursor){
  int i=blockIdx.x*blockDim.x+threadIdx.x;
  if(i<NN){
    int r=incl[i]+boff[i>>8];
    row_ptr[i+1]=r; cursor[i]=r-deg[i];
  }
  if(i==0) row_ptr[0]=0;
}

// CSR fill with source-node + edge-attr materialized in slot order
__global__ void k_fill_csr2(const int* __restrict__ ei, const float* __restrict__ ea,
    int* __restrict__ cursor, int* __restrict__ csr_src, float* __restrict__ eas){
  int e=blockIdx.x*blockDim.x+threadIdx.x;
  if(e<NE){
    int t=ei[NE+e]; int pos=atomicAdd(&cursor[t],1);
    csr_src[pos]=ei[e];
    const float* s=ea+(size_t)e*9;
    float* d=eas+(size_t)pos*12;
    #pragma unroll
    for(int k=0;k<9;++k) d[k]=s[k];
    d[9]=0.f; d[10]=0.f; d[11]=0.f;
  }
}

// stable counting-sort of pairs by type; tiles of 32 rows padded per group; islot = slot->output pos
__global__ __launch_bounds__(256) void k_sort(const int* __restrict__ types, int* __restrict__ meta,
    int* __restrict__ slotp, int* __restrict__ islot){
  __shared__ int cnt[256][8];
  __shared__ int tot[8];
  __shared__ int base_s[8], pad_s[8];
  int tid=threadIdx.x;
  int lc[8]={0,0,0,0,0,0,0,0};
  int tl[32];
  for(int i=0;i<32;++i){ int ty=types[tid*32+i]; tl[i]=ty; lc[ty]++; }
  #pragma unroll
  for(int t=0;t<8;++t) cnt[tid][t]=lc[t];
  __syncthreads();
  if(tid<8){
    int run=0;
    for(int j=0;j<256;++j){ int v=cnt[j][tid]; cnt[j][tid]=run; run+=v; }
    tot[tid]=run;
  }
  __syncthreads();
  if(tid==0){
    int b=0, pb=0, nt=0;
    for(int t=0;t<8;++t){
      base_s[t]=b; pad_s[t]=pb;
      meta[t]=tot[t]; meta[8+t]=b; meta[16+t]=pb;
      int ntt=(tot[t]+31)>>5;
      for(int j=0;j<ntt;++j){ meta[32+nt]=t; meta[32+MAXT+nt]=pb+j*32; nt++; }
      b+=tot[t]; pb+=ntt*32;
    }
    meta[24]=nt; meta[25]=pb;
  }
  __syncthreads();
  if(tid<8){
    int t=tid; int ntt=(tot[t]+31)>>5;
    for(int sr=tot[t]; sr<ntt*32; ++sr) islot[pad_s[t]+sr]=-1;
  }
  int run[8];
  #pragma unroll
  for(int t=0;t<8;++t) run[t]=cnt[tid][t];
  for(int i=0;i<32;++i){
    int p=tid*32+i; int t=tl[i]; int r=run[t]++;
    int pos=base_s[t]+r, slot=pad_s[t]+r;
    slotp[p]=slot; islot[slot]=pos;
  }
}

// node transform: grid 313x8, hsT[k][r] transposed staging -> float4 LDS reads both operands
__global__ __launch_bounds__(256) void k_nodexf(const float* __restrict__ hin,
    const float* __restrict__ Wl, const float* __restrict__ bl,
    const float* __restrict__ Wr, const float* __restrict__ br,
    float* __restrict__ xl, float* __restrict__ xr, int lk){
  __shared__ float hsT[64][68];
  __shared__ float ws[64][68];
  int bid=blockIdx.x;
  int n0=(bid>>3)*64, ch=bid&7;
  const float* W=(ch<4)?Wl:Wr;
  const float* bb=(ch<4)?bl:br;
  float* outp=(ch<4)?xl:xr;
  int c0=(ch&3)*64;
  int tid=threadIdx.x;

  for(int idx=tid; idx<64*16; idx+=256){
    int r=idx&63, kq=idx>>6;
    int n=n0+r;
    float4 v=make_float4(0.f,0.f,0.f,0.f);
    if(n<NN) v=*(const float4*)&hin[(size_t)n*64+kq*4];
    if(lk){
      v.x=v.x>0.f?v.x:0.01f*v.x; v.y=v.y>0.f?v.y:0.01f*v.y;
      v.z=v.z>0.f?v.z:0.01f*v.z; v.w=v.w>0.f?v.w:0.01f*v.w;
    }
    hsT[kq*4+0][r]=v.x; hsT[kq*4+1][r]=v.y; hsT[kq*4+2][r]=v.z; hsT[kq*4+3][r]=v.w;
  }
  for(int idx=tid; idx<64*16; idx+=256){
    int k=idx>>4, j4=idx&15;
    *(float4*)&ws[k][j4*4]=*(const float4*)&W[(size_t)k*256+c0+j4*4];
  }
  __syncthreads();

  int ty=tid>>4, tx=tid&15;
  float acc[4][4]={};
  #pragma unroll 4
  for(int k=0;k<64;++k){
    float4 a=*(const float4*)&hsT[k][4*ty];
    float4 b=*(const float4*)&ws[k][4*tx];
    float aa[4]={a.x,a.y,a.z,a.w}, bbv[4]={b.x,b.y,b.z,b.w};
    #pragma unroll
    for(int i=0;i<4;++i){
      #pragma unroll
      for(int j=0;j<4;++j) acc[i][j]=fmaf(aa[i],bbv[j],acc[i][j]);
    }
  }
  float4 bias4=*(const float4*)&bb[c0+4*tx];
  #pragma unroll
  for(int i=0;i<4;++i){
    int n=n0+4*ty+i;
    if(n<NN){
      float4 o=make_float4(acc[i][0]+bias4.x, acc[i][1]+bias4.y, acc[i][2]+bias4.z, acc[i][3]+bias4.w);
      *(float4*)&outp[(size_t)n*256+c0+4*tx]=o;
    }
  }
}

// fused GAT edge pipeline: sequential csr_src/eas streams + depth-8 rolling xl prefetch +
// DPP wave-sum; exp2 with log2e folded into att; leaky via fmax.
__global__ __launch_bounds__(256) void k_agg2(const float* __restrict__ xl, const float* __restrict__ xr,
    const float* __restrict__ eas, const int* __restrict__ csr_src, const int* __restrict__ row_ptr,
    const float* __restrict__ WeL, const float* __restrict__ attL,
    const float* __restrict__ biasL, const float* __restrict__ gates, int layer,
    const float* __restrict__ hprev, float* __restrict__ hout){
  __shared__ float red[4][64];
  int n=blockIdx.x, tid=threadIdx.x;
  float w0=WeL[tid],      w1=WeL[256+tid],  w2=WeL[512+tid],  w3=WeL[768+tid],  w4=WeL[1024+tid];
  float w5=WeL[1280+tid], w6=WeL[1536+tid], w7=WeL[1792+tid], w8=WeL[2048+tid];
  float att_t=attL[tid]*1.44269504089f;      // fold log2(e) -> exp2
  float xr_t=xr[(size_t)n*256+tid];
  int s=row_ptr[n], t=row_ptr[n+1];
  float den=0.f, acc=0.f;

  auto body=[&](float xlv, int j){
    const float4* ep=(const float4*)(eas+(size_t)j*12);
    float4 e0=ep[0], e1=ep[1];
    float e8=eas[(size_t)j*12+8];
    float ev=e0.x*w0+e0.y*w1+e0.z*w2+e0.w*w3+e1.x*w4+e1.y*w5+e1.z*w6+e1.w*w7+e8*w8;
    float m=xlv+xr_t+ev;
    m=fmaxf(m,0.2f*m);                      // leaky(0.2), slope>0 so max works
    float pt=dpp_sum64(m*att_t);
    float a=exp2f(pt);
    den+=a; acc+=a*xlv;
  };

  float x0=0.f,x1=0.f,x2=0.f,x3=0.f,x4=0.f,x5=0.f,x6=0.f,x7=0.f;
  if(s+0<t) x0=xl[(size_t)csr_src[s+0]*256+tid];
  if(s+1<t) x1=xl[(size_t)csr_src[s+1]*256+tid];
  if(s+2<t) x2=xl[(size_t)csr_src[s+2]*256+tid];
  if(s+3<t) x3=xl[(size_t)csr_src[s+3]*256+tid];
  if(s+4<t) x4=xl[(size_t)csr_src[s+4]*256+tid];
  if(s+5<t) x5=xl[(size_t)csr_src[s+5]*256+tid];
  if(s+6<t) x6=xl[(size_t)csr_src[s+6]*256+tid];
  if(s+7<t) x7=xl[(size_t)csr_src[s+7]*256+tid];
  int j=s;
  while(j+11<t){
    float y0=xl[(size_t)csr_src[j+8]*256+tid];
    float y1=xl[(size_t)csr_src[j+9]*256+tid];
    float y2=xl[(size_t)csr_src[j+10]*256+tid];
    float y3=xl[(size_t)csr_src[j+11]*256+tid];
    body(x0,j); body(x1,j+1); body(x2,j+2); body(x3,j+3);
    x0=x4; x1=x5; x2=x6; x3=x7;
    x4=y0; x5=y1; x6=y2; x7=y3;
    j+=4;
  }
  if(j<t){ body(x0,j); ++j; }
  if(j<t){ body(x1,j); ++j; }
  if(j<t){ body(x2,j); ++j; }
  if(j<t){ body(x3,j); ++j; }
  if(j<t){ body(x4,j); ++j; }
  if(j<t){ body(x5,j); ++j; }
  if(j<t){ body(x6,j); ++j; }
  if(j<t){ body(x7,j); ++j; }
  while(j<t){ body(xl[(size_t)csr_src[j]*256+tid], j); ++j; }

  float rdn=den>0.f?1.f/den:0.f;
  int h=tid>>6, cc=tid&63;
  red[h][cc]=acc*rdn;
  __syncthreads();
  if(tid<64){
    float mean=(red[0][tid]+red[1][tid]+red[2][tid]+red[3][tid])*0.25f + biasL[tid];
    float o;
    if(layer==0) o=mean;
    else{
      float hp=hprev[(size_t)n*64+tid];
      hp=hp>0.f?hp:0.01f*hp;
      float g=sigm(gates[layer-1]);
      o=g*mean+(1.f-g)*hp;
    }
    hout[(size_t)n*64+tid]=o;
  }
}

// z0[slot, 2c]=h[a,c], z0[slot,2c+1]=h[b,c]
__global__ void k_buildz(const float* __restrict__ hfin, const int* __restrict__ ecross,
    const int* __restrict__ slotp, float* __restrict__ z){
  int g=blockIdx.x*blockDim.x+threadIdx.x;
  if(g>=NP*64) return;
  int p=g>>6, c=g&63;
  int a=ecross[2*p], b=ecross[2*p+1];
  int slot=slotp[p];
  float2 v; v.x=hfin[(size_t)a*64+c]; v.y=hfin[(size_t)b*64+c];
  ((float2*)(z+(size_t)slot*128))[c]=v;
}

// W1 prep: per (er, chunk of 32 j): chunk-linear fp16 image [jl(32)][k(128)] with
// XOR swizzle ((jl*128+k) ^ ((jl&7)<<3)) baked in -> global_load_lds drops it verbatim.
__global__ __launch_bounds__(256) void k_prepw1(const float* __restrict__ src, _Float16* __restrict__ dst){
  __shared__ float lds[128][33];
  int bid=blockIdx.x, er=bid>>7, ch=bid&127;
  const float* s=src+(size_t)er*128*4096 + ch*32;
  int tid=threadIdx.x;
  for(int idx=tid; idx<128*32; idx+=256){ int k=idx>>5, jl=idx&31; lds[k][jl]=s[(size_t)k*4096+jl]; }
  __syncthreads();
  _Float16* d=dst+(size_t)bid*4096;
  for(int g=tid; g<512; g+=256){
    int jl=g>>4, k8=g&15;
    f16x8 v;
    #pragma unroll
    for(int t=0;t<8;++t) v[t]=(_Float16)lds[k8*8+t][jl];
    int elem=(jl*128+k8*8)^((jl&7)<<3);
    *(f16x8*)(&d[elem])=v;
  }
}

// W2 prep: per (er, chunk of 32 j): [n(128)][jl(32)] with XOR swizzle ((n*32+jl) ^ ((n&7)<<3)).
__global__ __launch_bounds__(256) void k_prepw2(const float* __restrict__ src, _Float16* __restrict__ dst){
  __shared__ float lds[32][130];
  int bid=blockIdx.x, er=bid>>7, ch=bid&127;
  const float* s=src+(size_t)er*4096*128 + (size_t)ch*32*128;
  int tid=threadIdx.x;
  for(int idx=tid; idx<32*128; idx+=256){ int j=idx>>7, n=idx&127; lds[j][n]=s[(size_t)j*128+n]; }
  __syncthreads();
  _Float16* d=dst+(size_t)bid*4096;
  for(int g=tid; g<512; g+=256){
    int n=g>>2, j8=g&3;
    f16x8 v;
    #pragma unroll
    for(int t=0;t<8;++t) v[t]=(_Float16)lds[j8*8+t][n];
    int elem=(n*32+j8*8)^((n&7)<<3);
    *(f16x8*)(&d[elem])=v;
  }
}

// MFMA res-block partial: ypart[hq] = relu(relu(z)@W1[:,hq-range]+b1) @ W2[hq-range,:]
__global__ __launch_bounds__(256) void k_resmfma(const float* __restrict__ zin,
    const _Float16* __restrict__ w1t, const _Float16* __restrict__ w2t,
    const float* __restrict__ b1all, const int* __restrict__ meta,
    float* __restrict__ ypart, int rb)
{
  __shared__ _Float16 zh[32*128];
  __shared__ _Float16 wb[2][8192];
  __shared__ _Float16 ts[32*32];
  __shared__ float b1s[1024];
  int bidl=blockIdx.x;
  int bid=(bidl&7)*132+(bidl>>3);
  int v=bid>>2, hq=bid&3;
  int nt=meta[24];
  if(v>=nt) return;
  int e=meta[32+v], row0=meta[32+MAXT+v];
  int er=e*2+rb;
  const _Float16* w1b=w1t+(size_t)er*524288 + (size_t)hq*32*4096;
  const _Float16* w2b=w2t+(size_t)er*524288 + (size_t)hq*32*4096;
  const float* b1g=b1all+(size_t)er*4096 + hq*1024;
  int tid=threadIdx.x, l=tid&63, w=tid>>6;
  int lm=l&15, lq=l>>4;
  int s16=(w&1)*16, jh=w>>1;
  int arow=s16+lm;

  for(int g=tid; g<512; g+=256){
    int row=g>>4, slot=g&15;
    const float* src=zin+(size_t)(row0+row)*128+slot*8;
    float4 v0=*(const float4*)src;
    float4 v1=*(const float4*)(src+4);
    f16x8 hv;
    hv[0]=(_Float16)fmaxf(v0.x,0.f); hv[1]=(_Float16)fmaxf(v0.y,0.f);
    hv[2]=(_Float16)fmaxf(v0.z,0.f); hv[3]=(_Float16)fmaxf(v0.w,0.f);
    hv[4]=(_Float16)fmaxf(v1.x,0.f); hv[5]=(_Float16)fmaxf(v1.y,0.f);
    hv[6]=(_Float16)fmaxf(v1.z,0.f); hv[7]=(_Float16)fmaxf(v1.w,0.f);
    *(f16x8*)(&zh[(row*128+slot*8)^((row&7)<<3)])=hv;
  }
  for(int g=tid; g<1024; g+=256) b1s[g]=b1g[g];

  #pragma unroll
  for(int s=0;s<2;++s){
    int so=(w*2+s)*512;
    GLL16(w1b+so+l*8, &wb[0][so]);
    GLL16(w2b+so+l*8, &wb[0][4096+so]);
  }
  asm volatile("s_waitcnt lgkmcnt(0)" ::: "memory");
  __builtin_amdgcn_sched_barrier(0);
  __builtin_amdgcn_s_barrier();

  f32x4 yacc[4];
  #pragma unroll
  for(int i=0;i<4;++i){ yacc[i][0]=0.f; yacc[i][1]=0.f; yacc[i][2]=0.f; yacc[i][3]=0.f; }

  for(int cc=0; cc<32; ++cc){
    int buf=cc&1;
    if(cc<31){
      const _Float16* g1=w1b+(size_t)(cc+1)*4096;
      const _Float16* g2=w2b+(size_t)(cc+1)*4096;
      int nb=buf^1;
      #pragma unroll
      for(int s=0;s<2;++s){
        int so=(w*2+s)*512;
        GLL16(g1+so+l*8, &wb[nb][so]);
        GLL16(g2+so+l*8, &wb[nb][4096+so]);
      }
      asm volatile("s_waitcnt vmcnt(4)" ::: "memory");
    }else{
      asm volatile("s_waitcnt vmcnt(0)" ::: "memory");
    }
    __builtin_amdgcn_sched_barrier(0);
    __builtin_amdgcn_s_barrier();

    f32x4 tacc={0.f,0.f,0.f,0.f};
    int j=jh*16+lm;
    #pragma unroll
    for(int ks=0;ks<4;++ks){
      f16x8 a=*(const f16x8*)(&zh[(arow*128+ks*32+lq*8)^((arow&7)<<3)]);
      f16x8 b=*(const f16x8*)(&wb[buf][(j*128+ks*32+lq*8)^((j&7)<<3)]);
      tacc=__builtin_amdgcn_mfma_f32_16x16x32_f16(a,b,tacc,0,0,0);
    }
    float b1v=b1s[cc*32+j];
    #pragma unroll
    for(int r=0;r<4;++r){
      int trow=s16+lq*4+r;
      ts[(trow*32+j)^((trow&7)<<3)]=(_Float16)fmaxf(tacc[r]+b1v,0.f);
    }
    asm volatile("s_waitcnt lgkmcnt(0)" ::: "memory");
    __builtin_amdgcn_sched_barrier(0);
    __builtin_amdgcn_s_barrier();

    f16x8 a2=*(const f16x8*)(&ts[(arow*32+lq*8)^((arow&7)<<3)]);
    #pragma unroll
    for(int nf=0;nf<4;++nf){
      int n=jh*64+nf*16+lm;
      f16x8 b=*(const f16x8*)(&wb[buf][4096+((n*32+lq*8)^((n&7)<<3))]);
      yacc[nf]=__builtin_amdgcn_mfma_f32_16x16x32_f16(a2,b,yacc[nf],0,0,0);
    }
    __builtin_amdgcn_s_barrier();
  }

  float* yp=ypart+(size_t)hq*CAPR*128;
  #pragma unroll
  for(int nf=0;nf<4;++nf){
    int col=jh*64+nf*16+lm;
    #pragma unroll
    for(int r=0;r<4;++r)
      yp[(size_t)(row0+s16+lq*4+r)*128+col]=yacc[nf][r];
  }
}

// combine 4 hid-quadrant partials + gated residual; rb==1 fuses head dot + ordered scatter
__global__ __launch_bounds__(256) void k_comb(const float* __restrict__ zin, const float* __restrict__ ypart,
    const float* __restrict__ b2all, const float* __restrict__ gates, const int* __restrict__ meta,
    int rb, float* __restrict__ zout,
    const float* __restrict__ hWg, const float* __restrict__ hbg, const int* __restrict__ islot,
    float* __restrict__ out)
{
  int v=blockIdx.x;
  if(v>=meta[24]) return;
  int e=meta[32+v], row0=meta[32+MAXT+v];
  int er=e*2+rb;
  float ge=sigm(gates[er]);
  const float* b2=b2all+(size_t)er*128;
  int tid=threadIdx.x;
  const size_t HS=(size_t)CAPR*128;
  if(rb==0){
    for(int idx=tid; idx<32*128; idx+=256){
      int r=idx>>7, c=idx&127;
      size_t o=(size_t)(row0+r)*128+c;
      float y=ypart[o]+ypart[HS+o]+ypart[2*HS+o]+ypart[3*HS+o];
      float zr=fmaxf(zin[o],0.f);
      zout[o]=ge*(y+b2[c])+(1.f-ge)*zr;
    }
  }else{
    int r=tid>>3, cs=tid&7;
    float acc=0.f;
    size_t ro=(size_t)(row0+r)*128;
    #pragma unroll
    for(int q=0;q<16;++q){
      int c=cs*16+q;
      size_t o=ro+c;
      float y=ypart[o]+ypart[HS+o]+ypart[2*HS+o]+ypart[3*HS+o];
      float zr=fmaxf(zin[o],0.f);
      float zf=ge*(y+b2[c])+(1.f-ge)*zr;
      acc+=zf*hWg[e*128+c];
    }
    acc+=__shfl_xor(acc,1); acc+=__shfl_xor(acc,2); acc+=__shfl_xor(acc,4);
    if(cs==0){
      int pos=islot[row0+r];
      if(pos>=0) out[pos]=acc+hbg[e];
    }
  }
}

extern "C" void kernel_launch(void* const* d_in, const int* in_sizes, int n_in,
                              void* d_out, int out_size, void* d_ws, size_t ws_size,
                              hipStream_t stream){
  const float* x     =(const float*)d_in[0];
  const int*   ei    =(const int*)  d_in[1];
  const float* ea    =(const float*)d_in[2];
  const int*   ecross=(const int*)  d_in[3];
  const int*   types =(const int*)  d_in[4];
  const float* gWl   =(const float*)d_in[5];
  const float* gbl   =(const float*)d_in[6];
  const float* gWr   =(const float*)d_in[7];
  const float* gbr   =(const float*)d_in[8];
  const float* gWe   =(const float*)d_in[9];
  const float* gatt  =(const float*)d_in[10];
  const float* gbias =(const float*)d_in[11];
  const float* ggate =(const float*)d_in[12];
  const float* rW1   =(const float*)d_in[13];
  const float* rb1   =(const float*)d_in[14];
  const float* rW2   =(const float*)d_in[15];
  const float* rb2   =(const float*)d_in[16];
  const float* rg    =(const float*)d_in[17];
  const float* hW    =(const float*)d_in[18];
  const float* hb    =(const float*)d_in[19];
  float* out=(float*)d_out;

  char* base=(char*)d_ws;
  size_t off=0;
  auto alloc=[&](size_t bytes)->char*{
    char* p=base+off;
    off=(off+bytes+511)&~((size_t)511);
    return p;
  };
  float* hA     =(float*)alloc((size_t)NN*64*4);
  float* hB     =(float*)alloc((size_t)NN*64*4);   // reused as zB in expert phase
  int*   deg    =(int*)  alloc((size_t)NN*4);
  int*   row_ptr=(int*)  alloc((size_t)(NN+1)*4);
  int*   cursor =(int*)  alloc((size_t)NN*4);
  int*   incl   =(int*)  alloc((size_t)NN*4);
  int*   bsum   =(int*)  alloc(256*4);
  int*   boff   =(int*)  alloc(256*4);
  int*   csr_src=(int*)  alloc((size_t)(NE+16)*4);
  int*   meta   =(int*)  alloc(1024*4);
  int*   slotp  =(int*)  alloc((size_t)NP*4);
  int*   islot  =(int*)  alloc((size_t)CAPR*4);
  float* zA     =(float*)alloc((size_t)CAPR*128*4);
  // union region: {xl, xr, eas} (GAT) overlaid with {w1t, w2t, ypart} (experts)
  size_t uoff=off;
  float* xl =(float*)(base+uoff);
  float* xr =(float*)(base+uoff+(size_t)NN*256*4);
  float* eas=(float*)(base+uoff+(size_t)NN*256*4*2);
  _Float16* w1t=(_Float16*)(base+uoff);
  _Float16* w2t=(_Float16*)(base+uoff+(size_t)16*524288*2);
  float* ypart =(float*)(base+uoff+(size_t)16*524288*2*2);
  size_t gat_bytes=(size_t)NN*256*4*2 + (size_t)(NE*12+16)*4;
  size_t exp_bytes=(size_t)16*524288*2*2 + (size_t)4*CAPR*128*4;
  size_t need=uoff+(gat_bytes>exp_bytes?gat_bytes:exp_bytes);
  if(ws_size<need) return;
  float* zB=hB;

  // ---- CSR by target (+src/ea materialization) + pair sort ----
  k_fill_i<<<(NN+255)/256,256,0,stream>>>(deg,NN,0);
  k_deg<<<(NE+255)/256,256,0,stream>>>(ei,deg);
  k_scan1<<<NB,256,0,stream>>>(deg,incl,bsum);
  k_scan2<<<1,64,0,stream>>>(bsum,boff);
  k_scan3<<<(NN+255)/256,256,0,stream>>>(deg,incl,boff,row_ptr,cursor);
  k_fill_csr2<<<(NE+255)/256,256,0,stream>>>(ei,ea,cursor,csr_src,eas);
  k_sort<<<1,256,0,stream>>>(types,meta,slotp,islot);

  // ---- GAT layers ----
  const float* hcur=x;
  float* hnext=hA;
  for(int L=0;L<NL;++L){
    k_nodexf<<<((NN+63)/64)*8,256,0,stream>>>(hcur, gWl+(size_t)L*64*256, gbl+(size_t)L*256,
                                              gWr+(size_t)L*64*256, gbr+(size_t)L*256, xl, xr, L>0?1:0);
    k_agg2<<<NN,256,0,stream>>>(xl,xr,eas,csr_src,row_ptr, gWe+(size_t)L*EDIM*256,
                                gatt+(size_t)L*256, gbias+(size_t)L*64, ggate, L, hcur, hnext);
    hcur=hnext;
    hnext=(hcur==hA)?hB:hA;
  }
  // hcur == hA after 3 layers; hB is dead -> zB overlay is safe

  // ---- pair gather into type-sorted padded layout ----
  k_buildz<<<NP*64/256,256,0,stream>>>(hcur,ecross,slotp,zA);

  // ---- weight prep: fp16, chunked, transposed, swizzle baked in (xl/xr/eas now dead) ----
  k_prepw1<<<2048,256,0,stream>>>(rW1,w1t);
  k_prepw2<<<2048,256,0,stream>>>(rW2,w2t);

  // ---- routed experts: 2 res-blocks, each = MFMA partial + combine ----
  k_resmfma<<<1056,256,0,stream>>>(zA,w1t,w2t,rb1,meta,ypart,0);
  k_comb<<<MAXT,256,0,stream>>>(zA,ypart,rb2,rg,meta,0,zB,hW,hb,islot,out);
  k_resmfma<<<1056,256,0,stream>>>(zB,w1t,w2t,rb1,meta,ypart,1);
  k_comb<<<MAXT,256,0,stream>>>(zB,ypart,rb2,rg,meta,1,zA,hW,hb,islot,out);

  (void)in_sizes; (void)n_in; (void)out_size;
}

// Round 13
// 551.532 us; speedup vs baseline: 1.3246x; 1.0491x over previous
//
#include <hip/hip_runtime.h>

#define NN 20000
#define NE 320000
#define NL 3
#define NP 8192
#define EDIM 9
#define TROWS 32
#define MAXT 272
#define CAPR (MAXT*TROWS)
#define NB ((NN+255)/256)

typedef _Float16 f16x8 __attribute__((ext_vector_type(8)));
typedef float f32x4 __attribute__((ext_vector_type(4)));

#define GLL16(g,l) __builtin_amdgcn_global_load_lds((const __attribute__((address_space(1))) unsigned int*)(g), (__attribute__((address_space(3))) unsigned int*)(l), 16, 0, 0)

__device__ __forceinline__ float sigm(float x){ return 1.f/(1.f+__expf(-x)); }

// wave64 sum via DPP through compiler intrinsics (hazard-safe; round-7 proven)
__device__ __forceinline__ float dpp_sum64(float x){
  x += __int_as_float(__builtin_amdgcn_update_dpp(0, __float_as_int(x), 0x111, 0xf, 0xf, true));
  x += __int_as_float(__builtin_amdgcn_update_dpp(0, __float_as_int(x), 0x112, 0xf, 0xf, true));
  x += __int_as_float(__builtin_amdgcn_update_dpp(0, __float_as_int(x), 0x114, 0xf, 0xf, true));
  x += __int_as_float(__builtin_amdgcn_update_dpp(0, __float_as_int(x), 0x118, 0xf, 0xf, true));
  x += __int_as_float(__builtin_amdgcn_update_dpp(0, __float_as_int(x), 0x142, 0xf, 0xf, true));
  x += __int_as_float(__builtin_amdgcn_update_dpp(0, __float_as_int(x), 0x143, 0xf, 0xf, true));
  return __uint_as_float(__builtin_amdgcn_readlane(__float_as_uint(x), 63));
}

__global__ void k_fill_i(int* __restrict__ p, int n, int v){ int i=blockIdx.x*blockDim.x+threadIdx.x; if(i<n)p[i]=v; }

__global__ void k_deg(const int* __restrict__ ei, int* __restrict__ deg){
  int e=blockIdx.x*blockDim.x+threadIdx.x; if(e<NE) atomicAdd(&deg[ei[NE+e]],1);
}

// ---- parallel 3-phase scan ----
__global__ __launch_bounds__(256) void k_scan1(const int* __restrict__ deg, int* __restrict__ incl, int* __restrict__ bsum){
  __shared__ int sh[256];
  int b=blockIdx.x, tid=threadIdx.x;
  int i=b*256+tid;
  int v=(i<NN)?deg[i]:0;
  sh[tid]=v; __syncthreads();
  for(int o=1;o<256;o<<=1){
    int t=(tid>=o)?sh[tid-o]:0; __syncthreads();
    sh[tid]+=t; __syncthreads();
  }
  if(i<NN) incl[i]=sh[tid];
  if(tid==255) bsum[b]=sh[255];
}
__global__ void k_scan2(const int* __restrict__ bsum, int* __restrict__ boff){
  if(blockIdx.x==0 && threadIdx.x==0){
    int run=0;
    for(int b=0;b<NB;++b){ boff[b]=run; run+=bsum[b]; }
  }
}
__global__ void k_scan3(const int* __restrict__ deg, const int* __restrict__ incl,
                        const int* __restrict__ boff, int* __restrict__ row_ptr, int* __restrict__ cursor){
  int i=blockIdx.x*blockDim.x+threadIdx.x;
  if(i<NN){
    int r=incl[i]+boff[i>>8];
    row_ptr[i+1]=r; cursor[i]=r-deg[i];
  }
  if(i==0) row_ptr[0]=0;
}

// CSR fill with source-node + edge-attr materialized in slot order
__global__ void k_fill_csr2(const int* __restrict__ ei, const float* __restrict__ ea,
    int* __restrict__ cursor, int* __restrict__ csr_src, float* __restrict__ eas){
  int e=blockIdx.x*blockDim.x+threadIdx.x;
  if(e<NE){
    int t=ei[NE+e]; int pos=atomicAdd(&cursor[t],1);
    csr_src[pos]=ei[e];
    const float* s=ea+(size_t)e*9;
    float* d=eas+(size_t)pos*12;
    #pragma unroll
    for(int k=0;k<9;++k) d[k]=s[k];
    d[9]=0.f; d[10]=0.f; d[11]=0.f;
  }
}

// stable counting-sort of pairs by type; tiles of 32 rows padded per group; islot = slot->output pos
__global__ __launch_bounds__(256) void k_sort(const int* __restrict__ types, int* __restrict__ meta,
    int* __restrict__ slotp, int* __restrict__ islot){
  __shared__ int cnt[256][8];
  __shared__ int tot[8];
  __shared__ int base_s[8], pad_s[8];
  int tid=threadIdx.x;
  int lc[8]={0,0,0,0,0,0,0,0};
  int tl[32];
  for(int i=0;i<32;++i){ int ty=types[tid*32+i]; tl[i]=ty; lc[ty]++; }
  #pragma unroll
  for(int t=0;t<8;++t) cnt[tid][t]=lc[t];
  __syncthreads();
  if(tid<8){
    int run=0;
    for(int j=0;j<256;++j){ int v=cnt[j][tid]; cnt[j][tid]=run; run+=v; }
    tot[tid]=run;
  }
  __syncthreads();
  if(tid==0){
    int b=0, pb=0, nt=0;
    for(int t=0;t<8;++t){
      base_s[t]=b; pad_s[t]=pb;
      meta[t]=tot[t]; meta[8+t]=b; meta[16+t]=pb;
      int ntt=(tot[t]+31)>>5;
      for(int j=0;j<ntt;++j){ meta[32+nt]=t; meta[32+MAXT+nt]=pb+j*32; nt++; }
      b+=tot[t]; pb+=ntt*32;
    }
    meta[24]=nt; meta[25]=pb;
  }
  __syncthreads();
  if(tid<8){
    int t=tid; int ntt=(tot[t]+31)>>5;
    for(int sr=tot[t]; sr<ntt*32; ++sr) islot[pad_s[t]+sr]=-1;
  }
  int run[8];
  #pragma unroll
  for(int t=0;t<8;++t) run[t]=cnt[tid][t];
  for(int i=0;i<32;++i){
    int p=tid*32+i; int t=tl[i]; int r=run[t]++;
    int pos=base_s[t]+r, slot=pad_s[t]+r;
    slotp[p]=slot; islot[slot]=pos;
  }
}

// node transform: grid 313x8, hsT[k][r] transposed staging -> float4 LDS reads both operands
__global__ __launch_bounds__(256) void k_nodexf(const float* __restrict__ hin,
    const float* __restrict__ Wl, const float* __restrict__ bl,
    const float* __restrict__ Wr, const float* __restrict__ br,
    float* __restrict__ xl, float* __restrict__ xr, int lk){
  __shared__ float hsT[64][68];
  __shared__ float ws[64][68];
  int bid=blockIdx.x;
  int n0=(bid>>3)*64, ch=bid&7;
  const float* W=(ch<4)?Wl:Wr;
  const float* bb=(ch<4)?bl:br;
  float* outp=(ch<4)?xl:xr;
  int c0=(ch&3)*64;
  int tid=threadIdx.x;

  for(int idx=tid; idx<64*16; idx+=256){
    int r=idx&63, kq=idx>>6;
    int n=n0+r;
    float4 v=make_float4(0.f,0.f,0.f,0.f);
    if(n<NN) v=*(const float4*)&hin[(size_t)n*64+kq*4];
    if(lk){
      v.x=v.x>0.f?v.x:0.01f*v.x; v.y=v.y>0.f?v.y:0.01f*v.y;
      v.z=v.z>0.f?v.z:0.01f*v.z; v.w=v.w>0.f?v.w:0.01f*v.w;
    }
    hsT[kq*4+0][r]=v.x; hsT[kq*4+1][r]=v.y; hsT[kq*4+2][r]=v.z; hsT[kq*4+3][r]=v.w;
  }
  for(int idx=tid; idx<64*16; idx+=256){
    int k=idx>>4, j4=idx&15;
    *(float4*)&ws[k][j4*4]=*(const float4*)&W[(size_t)k*256+c0+j4*4];
  }
  __syncthreads();

  int ty=tid>>4, tx=tid&15;
  float acc[4][4]={};
  #pragma unroll 4
  for(int k=0;k<64;++k){
    float4 a=*(const float4*)&hsT[k][4*ty];
    float4 b=*(const float4*)&ws[k][4*tx];
    float aa[4]={a.x,a.y,a.z,a.w}, bbv[4]={b.x,b.y,b.z,b.w};
    #pragma unroll
    for(int i=0;i<4;++i){
      #pragma unroll
      for(int j=0;j<4;++j) acc[i][j]=fmaf(aa[i],bbv[j],acc[i][j]);
    }
  }
  float4 bias4=*(const float4*)&bb[c0+4*tx];
  #pragma unroll
  for(int i=0;i<4;++i){
    int n=n0+4*ty+i;
    if(n<NN){
      float4 o=make_float4(acc[i][0]+bias4.x, acc[i][1]+bias4.y, acc[i][2]+bias4.z, acc[i][3]+bias4.w);
      *(float4*)&outp[(size_t)n*256+c0+4*tx]=o;
    }
  }
}

// fused GAT edge pipeline (round-11 proven): sequential csr_src/eas streams +
// depth-4 rolling xl prefetch + DPP wave-sum
__global__ __launch_bounds__(256) void k_agg2(const float* __restrict__ xl, const float* __restrict__ xr,
    const float* __restrict__ eas, const int* __restrict__ csr_src, const int* __restrict__ row_ptr,
    const float* __restrict__ WeL, const float* __restrict__ attL,
    const float* __restrict__ biasL, const float* __restrict__ gates, int layer,
    const float* __restrict__ hprev, float* __restrict__ hout){
  __shared__ float red[4][64];
  int n=blockIdx.x, tid=threadIdx.x;
  float w0=WeL[tid],      w1=WeL[256+tid],  w2=WeL[512+tid],  w3=WeL[768+tid],  w4=WeL[1024+tid];
  float w5=WeL[1280+tid], w6=WeL[1536+tid], w7=WeL[1792+tid], w8=WeL[2048+tid];
  float att_t=attL[tid];
  float xr_t=xr[(size_t)n*256+tid];
  int s=row_ptr[n], t=row_ptr[n+1];
  float den=0.f, acc=0.f;

  auto body=[&](float xlv, int j){
    const float4* ep=(const float4*)(eas+(size_t)j*12);
    float4 e0=ep[0], e1=ep[1];
    float e8=eas[(size_t)j*12+8];
    float ev=e0.x*w0+e0.y*w1+e0.z*w2+e0.w*w3+e1.x*w4+e1.y*w5+e1.z*w6+e1.w*w7+e8*w8;
    float m=xlv+xr_t+ev;
    m=m>0.f?m:0.2f*m;
    float pt=dpp_sum64(m*att_t);
    float a=__expf(pt);
    den+=a; acc+=a*xlv;
  };

  float x0=0.f,x1=0.f,x2=0.f,x3=0.f;
  if(s+0<t) x0=xl[(size_t)csr_src[s+0]*256+tid];
  if(s+1<t) x1=xl[(size_t)csr_src[s+1]*256+tid];
  if(s+2<t) x2=xl[(size_t)csr_src[s+2]*256+tid];
  if(s+3<t) x3=xl[(size_t)csr_src[s+3]*256+tid];
  int j=s;
  while(j+7<t){
    float y0=xl[(size_t)csr_src[j+4]*256+tid];
    float y1=xl[(size_t)csr_src[j+5]*256+tid];
    float y2=xl[(size_t)csr_src[j+6]*256+tid];
    float y3=xl[(size_t)csr_src[j+7]*256+tid];
    body(x0,j); body(x1,j+1); body(x2,j+2); body(x3,j+3);
    x0=y0; x1=y1; x2=y2; x3=y3;
    j+=4;
  }
  if(j<t){ body(x0,j); ++j; }
  if(j<t){ body(x1,j); ++j; }
  if(j<t){ body(x2,j); ++j; }
  if(j<t){ body(x3,j); ++j; }
  while(j<t){ body(xl[(size_t)csr_src[j]*256+tid], j); ++j; }

  float rdn=den>0.f?1.f/den:0.f;
  int h=tid>>6, cc=tid&63;
  red[h][cc]=acc*rdn;
  __syncthreads();
  if(tid<64){
    float mean=(red[0][tid]+red[1][tid]+red[2][tid]+red[3][tid])*0.25f + biasL[tid];
    float o;
    if(layer==0) o=mean;
    else{
      float hp=hprev[(size_t)n*64+tid];
      hp=hp>0.f?hp:0.01f*hp;
      float g=sigm(gates[layer-1]);
      o=g*mean+(1.f-g)*hp;
    }
    hout[(size_t)n*64+tid]=o;
  }
}

// z0[slot, 2c]=h[a,c], z0[slot,2c+1]=h[b,c]
__global__ void k_buildz(const float* __restrict__ hfin, const int* __restrict__ ecross,
    const int* __restrict__ slotp, float* __restrict__ z){
  int g=blockIdx.x*blockDim.x+threadIdx.x;
  if(g>=NP*64) return;
  int p=g>>6, c=g&63;
  int a=ecross[2*p], b=ecross[2*p+1];
  int slot=slotp[p];
  float2 v; v.x=hfin[(size_t)a*64+c]; v.y=hfin[(size_t)b*64+c];
  ((float2*)(z+(size_t)slot*128))[c]=v;
}

// W1 prep: per (er, chunk of 32 j): chunk-linear fp16 image [jl(32)][k(128)] with
// XOR swizzle ((jl*128+k) ^ ((jl&7)<<3)) baked in -> global_load_lds drops it verbatim.
__global__ __launch_bounds__(256) void k_prepw1(const float* __restrict__ src, _Float16* __restrict__ dst){
  __shared__ float lds[128][33];
  int bid=blockIdx.x, er=bid>>7, ch=bid&127;
  const float* s=src+(size_t)er*128*4096 + ch*32;
  int tid=threadIdx.x;
  for(int idx=tid; idx<128*32; idx+=256){ int k=idx>>5, jl=idx&31; lds[k][jl]=s[(size_t)k*4096+jl]; }
  __syncthreads();
  _Float16* d=dst+(size_t)bid*4096;
  for(int g=tid; g<512; g+=256){
    int jl=g>>4, k8=g&15;
    f16x8 v;
    #pragma unroll
    for(int t=0;t<8;++t) v[t]=(_Float16)lds[k8*8+t][jl];
    int elem=(jl*128+k8*8)^((jl&7)<<3);
    *(f16x8*)(&d[elem])=v;
  }
}

// W2 prep: per (er, chunk of 32 j): [n(128)][jl(32)] with XOR swizzle ((n*32+jl) ^ ((n&7)<<3)).
__global__ __launch_bounds__(256) void k_prepw2(const float* __restrict__ src, _Float16* __restrict__ dst){
  __shared__ float lds[32][130];
  int bid=blockIdx.x, er=bid>>7, ch=bid&127;
  const float* s=src+(size_t)er*4096*128 + (size_t)ch*32*128;
  int tid=threadIdx.x;
  for(int idx=tid; idx<32*128; idx+=256){ int j=idx>>7, n=idx&127; lds[j][n]=s[(size_t)j*128+n]; }
  __syncthreads();
  _Float16* d=dst+(size_t)bid*4096;
  for(int g=tid; g<512; g+=256){
    int n=g>>2, j8=g&3;
    f16x8 v;
    #pragma unroll
    for(int t=0;t<8;++t) v[t]=(_Float16)lds[j8*8+t][n];
    int elem=(n*32+j8*8)^((n&7)<<3);
    *(f16x8*)(&d[elem])=v;
  }
}

// MFMA res-block partial: ypart[hq] = relu(relu(z)@W1[:,hq-range]+b1) @ W2[hq-range,:]
__global__ __launch_bounds__(256) void k_resmfma(const float* __restrict__ zin,
    const _Float16* __restrict__ w1t, const _Float16* __restrict__ w2t,
    const float* __restrict__ b1all, const int* __restrict__ meta,
    float* __restrict__ ypart, int rb)
{
  __shared__ _Float16 zh[32*128];
  __shared__ _Float16 wb[2][8192];
  __shared__ _Float16 ts[32*32];
  __shared__ float b1s[1024];
  int bidl=blockIdx.x;
  int bid=(bidl&7)*132+(bidl>>3);
  int v=bid>>2, hq=bid&3;
  int nt=meta[24];
  if(v>=nt) return;
  int e=meta[32+v], row0=meta[32+MAXT+v];
  int er=e*2+rb;
  const _Float16* w1b=w1t+(size_t)er*524288 + (size_t)hq*32*4096;
  const _Float16* w2b=w2t+(size_t)er*524288 + (size_t)hq*32*4096;
  const float* b1g=b1all+(size_t)er*4096 + hq*1024;
  int tid=threadIdx.x, l=tid&63, w=tid>>6;
  int lm=l&15, lq=l>>4;
  int s16=(w&1)*16, jh=w>>1;
  int arow=s16+lm;

  for(int g=tid; g<512; g+=256){
    int row=g>>4, slot=g&15;
    const float* src=zin+(size_t)(row0+row)*128+slot*8;
    float4 v0=*(const float4*)src;
    float4 v1=*(const float4*)(src+4);
    f16x8 hv;
    hv[0]=(_Float16)fmaxf(v0.x,0.f); hv[1]=(_Float16)fmaxf(v0.y,0.f);
    hv[2]=(_Float16)fmaxf(v0.z,0.f); hv[3]=(_Float16)fmaxf(v0.w,0.f);
    hv[4]=(_Float16)fmaxf(v1.x,0.f); hv[5]=(_Float16)fmaxf(v1.y,0.f);
    hv[6]=(_Float16)fmaxf(v1.z,0.f); hv[7]=(_Float16)fmaxf(v1.w,0.f);
    *(f16x8*)(&zh[(row*128+slot*8)^((row&7)<<3)])=hv;
  }
  for(int g=tid; g<1024; g+=256) b1s[g]=b1g[g];

  #pragma unroll
  for(int s=0;s<2;++s){
    int so=(w*2+s)*512;
    GLL16(w1b+so+l*8, &wb[0][so]);
    GLL16(w2b+so+l*8, &wb[0][4096+so]);
  }
  asm volatile("s_waitcnt lgkmcnt(0)" ::: "memory");
  __builtin_amdgcn_sched_barrier(0);
  __builtin_amdgcn_s_barrier();

  f32x4 yacc[4];
  #pragma unroll
  for(int i=0;i<4;++i){ yacc[i][0]=0.f; yacc[i][1]=0.f; yacc[i][2]=0.f; yacc[i][3]=0.f; }

  for(int cc=0; cc<32; ++cc){
    int buf=cc&1;
    if(cc<31){
      const _Float16* g1=w1b+(size_t)(cc+1)*4096;
      const _Float16* g2=w2b+(size_t)(cc+1)*4096;
      int nb=buf^1;
      #pragma unroll
      for(int s=0;s<2;++s){
        int so=(w*2+s)*512;
        GLL16(g1+so+l*8, &wb[nb][so]);
        GLL16(g2+so+l*8, &wb[nb][4096+so]);
      }
      asm volatile("s_waitcnt vmcnt(4)" ::: "memory");
    }else{
      asm volatile("s_waitcnt vmcnt(0)" ::: "memory");
    }
    __builtin_amdgcn_sched_barrier(0);
    __builtin_amdgcn_s_barrier();

    f32x4 tacc={0.f,0.f,0.f,0.f};
    int j=jh*16+lm;
    #pragma unroll
    for(int ks=0;ks<4;++ks){
      f16x8 a=*(const f16x8*)(&zh[(arow*128+ks*32+lq*8)^((arow&7)<<3)]);
      f16x8 b=*(const f16x8*)(&wb[buf][(j*128+ks*32+lq*8)^((j&7)<<3)]);
      tacc=__builtin_amdgcn_mfma_f32_16x16x32_f16(a,b,tacc,0,0,0);
    }
    float b1v=b1s[cc*32+j];
    #pragma unroll
    for(int r=0;r<4;++r){
      int trow=s16+lq*4+r;
      ts[(trow*32+j)^((trow&7)<<3)]=(_Float16)fmaxf(tacc[r]+b1v,0.f);
    }
    asm volatile("s_waitcnt lgkmcnt(0)" ::: "memory");
    __builtin_amdgcn_sched_barrier(0);
    __builtin_amdgcn_s_barrier();

    f16x8 a2=*(const f16x8*)(&ts[(arow*32+lq*8)^((arow&7)<<3)]);
    #pragma unroll
    for(int nf=0;nf<4;++nf){
      int n=jh*64+nf*16+lm;
      f16x8 b=*(const f16x8*)(&wb[buf][4096+((n*32+lq*8)^((n&7)<<3))]);
      yacc[nf]=__builtin_amdgcn_mfma_f32_16x16x32_f16(a2,b,yacc[nf],0,0,0);
    }
    __builtin_amdgcn_s_barrier();
  }

  float* yp=ypart+(size_t)hq*CAPR*128;
  #pragma unroll
  for(int nf=0;nf<4;++nf){
    int col=jh*64+nf*16+lm;
    #pragma unroll
    for(int r=0;r<4;++r)
      yp[(size_t)(row0+s16+lq*4+r)*128+col]=yacc[nf][r];
  }
}

// combine 4 hid-quadrant partials + gated residual; rb==1 fuses head dot + ordered scatter
__global__ __launch_bounds__(256) void k_comb(const float* __restrict__ zin, const float* __restrict__ ypart,
    const float* __restrict__ b2all, const float* __restrict__ gates, const int* __restrict__ meta,
    int rb, float* __restrict__ zout,
    const float* __restrict__ hWg, const float* __restrict__ hbg, const int* __restrict__ islot,
    float* __restrict__ out)
{
  int v=blockIdx.x;
  if(v>=meta[24]) return;
  int e=meta[32+v], row0=meta[32+MAXT+v];
  int er=e*2+rb;
  float ge=sigm(gates[er]);
  const float* b2=b2all+(size_t)er*128;
  int tid=threadIdx.x;
  const size_t HS=(size_t)CAPR*128;
  if(rb==0){
    for(int idx=tid; idx<32*128; idx+=256){
      int r=idx>>7, c=idx&127;
      size_t o=(size_t)(row0+r)*128+c;
      float y=ypart[o]+ypart[HS+o]+ypart[2*HS+o]+ypart[3*HS+o];
      float zr=fmaxf(zin[o],0.f);
      zout[o]=ge*(y+b2[c])+(1.f-ge)*zr;
    }
  }else{
    int r=tid>>3, cs=tid&7;
    float acc=0.f;
    size_t ro=(size_t)(row0+r)*128;
    #pragma unroll
    for(int q=0;q<16;++q){
      int c=cs*16+q;
      size_t o=ro+c;
      float y=ypart[o]+ypart[HS+o]+ypart[2*HS+o]+ypart[3*HS+o];
      float zr=fmaxf(zin[o],0.f);
      float zf=ge*(y+b2[c])+(1.f-ge)*zr;
      acc+=zf*hWg[e*128+c];
    }
    acc+=__shfl_xor(acc,1); acc+=__shfl_xor(acc,2); acc+=__shfl_xor(acc,4);
    if(cs==0){
      int pos=islot[row0+r];
      if(pos>=0) out[pos]=acc+hbg[e];
    }
  }
}

extern "C" void kernel_launch(void* const* d_in, const int* in_sizes, int n_in,
                              void* d_out, int out_size, void* d_ws, size_t ws_size,
                              hipStream_t stream){
  const float* x     =(const float*)d_in[0];
  const int*   ei    =(const int*)  d_in[1];
  const float* ea    =(const float*)d_in[2];
  const int*   ecross=(const int*)  d_in[3];
  const int*   types =(const int*)  d_in[4];
  const float* gWl   =(const float*)d_in[5];
  const float* gbl   =(const float*)d_in[6];
  const float* gWr   =(const float*)d_in[7];
  const float* gbr   =(const float*)d_in[8];
  const float* gWe   =(const float*)d_in[9];
  const float* gatt  =(const float*)d_in[10];
  const float* gbias =(const float*)d_in[11];
  const float* ggate =(const float*)d_in[12];
  const float* rW1   =(const float*)d_in[13];
  const float* rb1   =(const float*)d_in[14];
  const float* rW2   =(const float*)d_in[15];
  const float* rb2   =(const float*)d_in[16];
  const float* rg    =(const float*)d_in[17];
  const float* hW    =(const float*)d_in[18];
  const float* hb    =(const float*)d_in[19];
  float* out=(float*)d_out;

  char* base=(char*)d_ws;
  size_t off=0;
  auto alloc=[&](size_t bytes)->char*{
    char* p=base+off;
    off=(off+bytes+511)&~((size_t)511);
    return p;
  };
  float* hA     =(float*)alloc((size_t)NN*64*4);
  float* hB     =(float*)alloc((size_t)NN*64*4);   // reused as zB in expert phase
  int*   deg    =(int*)  alloc((size_t)NN*4);
  int*   row_ptr=(int*)  alloc((size_t)(NN+1)*4);
  int*   cursor =(int*)  alloc((size_t)NN*4);
  int*   incl   =(int*)  alloc((size_t)NN*4);
  int*   bsum   =(int*)  alloc(256*4);
  int*   boff   =(int*)  alloc(256*4);
  int*   csr_src=(int*)  alloc((size_t)(NE+16)*4);
  int*   meta   =(int*)  alloc(1024*4);
  int*   slotp  =(int*)  alloc((size_t)NP*4);
  int*   islot  =(int*)  alloc((size_t)CAPR*4);
  float* zA     =(float*)alloc((size_t)CAPR*128*4);
  // union region: {xl, xr, eas} (GAT) overlaid with {w1t, w2t, ypart} (experts)
  size_t uoff=off;
  float* xl =(float*)(base+uoff);
  float* xr =(float*)(base+uoff+(size_t)NN*256*4);
  float* eas=(float*)(base+uoff+(size_t)NN*256*4*2);
  _Float16* w1t=(_Float16*)(base+uoff);
  _Float16* w2t=(_Float16*)(base+uoff+(size_t)16*524288*2);
  float* ypart =(float*)(base+uoff+(size_t)16*524288*2*2);
  size_t gat_bytes=(size_t)NN*256*4*2 + (size_t)(NE*12+16)*4;
  size_t exp_bytes=(size_t)16*524288*2*2 + (size_t)4*CAPR*128*4;
  size_t need=uoff+(gat_bytes>exp_bytes?gat_bytes:exp_bytes);
  if(ws_size<need) return;
  float* zB=hB;

  // ---- CSR by target (+src/ea materialization) + pair sort ----
  k_fill_i<<<(NN+255)/256,256,0,stream>>>(deg,NN,0);
  k_deg<<<(NE+255)/256,256,0,stream>>>(ei,deg);
  k_scan1<<<NB,256,0,stream>>>(deg,incl,bsum);
  k_scan2<<<1,64,0,stream>>>(bsum,boff);
  k_scan3<<<(NN+255)/256,256,0,stream>>>(deg,incl,boff,row_ptr,cursor);
  k_fill_csr2<<<(NE+255)/256,256,0,stream>>>(ei,ea,cursor,csr_src,eas);
  k_sort<<<1,256,0,stream>>>(types,meta,slotp,islot);

  // ---- GAT layers ----
  const float* hcur=x;
  float* hnext=hA;
  for(int L=0;L<NL;++L){
    k_nodexf<<<((NN+63)/64)*8,256,0,stream>>>(hcur, gWl+(size_t)L*64*256, gbl+(size_t)L*256,
                                              gWr+(size_t)L*64*256, gbr+(size_t)L*256, xl, xr, L>0?1:0);
    k_agg2<<<NN,256,0,stream>>>(xl,xr,eas,csr_src,row_ptr, gWe+(size_t)L*EDIM*256,
                                gatt+(size_t)L*256, gbias+(size_t)L*64, ggate, L, hcur, hnext);
    hcur=hnext;
    hnext=(hcur==hA)?hB:hA;
  }
  // hcur == hA after 3 layers; hB is dead -> zB overlay is safe

  // ---- pair gather into type-sorted padded layout ----
  k_buildz<<<NP*64/256,256,0,stream>>>(hcur,ecross,slotp,zA);

  // ---- weight prep: fp16, chunked, transposed, swizzle baked in (xl/xr/eas now dead) ----
  k_prepw1<<<2048,256,0,stream>>>(rW1,w1t);
  k_prepw2<<<2048,256,0,stream>>>(rW2,w2t);

  // ---- routed experts: 2 res-blocks, each = MFMA partial + combine ----
  k_resmfma<<<1056,256,0,stream>>>(zA,w1t,w2t,rb1,meta,ypart,0);
  k_comb<<<MAXT,256,0,stream>>>(zA,ypart,rb2,rg,meta,0,zB,hW,hb,islot,out);
  k_resmfma<<<1056,256,0,stream>>>(zB,w1t,w2t,rb1,meta,ypart,1);
  k_comb<<<MAXT,256,0,stream>>>(zB,ypart,rb2,rg,meta,1,zA,hW,hb,islot,out);

  (void)in_sizes; (void)n_in; (void)out_size;
}

// Round 14
// 550.155 us; speedup vs baseline: 1.3279x; 1.0025x over previous
//
#include <hip/hip_runtime.h>

#define NN 20000
#define NE 320000
#define NL 3
#define NP 8192
#define EDIM 9
#define TROWS 32
#define MAXT 272
#define CAPR (MAXT*TROWS)
#define NB ((NN+255)/256)

typedef _Float16 f16x8 __attribute__((ext_vector_type(8)));
typedef float f32x4 __attribute__((ext_vector_type(4)));

#define GLL16(g,l) __builtin_amdgcn_global_load_lds((const __attribute__((address_space(1))) unsigned int*)(g), (__attribute__((address_space(3))) unsigned int*)(l), 16, 0, 0)

__device__ __forceinline__ float sigm(float x){ return 1.f/(1.f+__expf(-x)); }

// wave64 sum via DPP through compiler intrinsics (hazard-safe; round-7 proven)
__device__ __forceinline__ float dpp_sum64(float x){
  x += __int_as_float(__builtin_amdgcn_update_dpp(0, __float_as_int(x), 0x111, 0xf, 0xf, true));
  x += __int_as_float(__builtin_amdgcn_update_dpp(0, __float_as_int(x), 0x112, 0xf, 0xf, true));
  x += __int_as_float(__builtin_amdgcn_update_dpp(0, __float_as_int(x), 0x114, 0xf, 0xf, true));
  x += __int_as_float(__builtin_amdgcn_update_dpp(0, __float_as_int(x), 0x118, 0xf, 0xf, true));
  x += __int_as_float(__builtin_amdgcn_update_dpp(0, __float_as_int(x), 0x142, 0xf, 0xf, true));
  x += __int_as_float(__builtin_amdgcn_update_dpp(0, __float_as_int(x), 0x143, 0xf, 0xf, true));
  return __uint_as_float(__builtin_amdgcn_readlane(__float_as_uint(x), 63));
}

__global__ void k_deg(const int* __restrict__ ei, int* __restrict__ deg){
  int e=blockIdx.x*blockDim.x+threadIdx.x; if(e<NE) atomicAdd(&deg[ei[NE+e]],1);
}

// ---- parallel scan: block-local inclusive scan, then per-block offset computed in scan3 ----
__global__ __launch_bounds__(256) void k_scan1(const int* __restrict__ deg, int* __restrict__ incl, int* __restrict__ bsum){
  __shared__ int sh[256];
  int b=blockIdx.x, tid=threadIdx.x;
  int i=b*256+tid;
  int v=(i<NN)?deg[i]:0;
  sh[tid]=v; __syncthreads();
  for(int o=1;o<256;o<<=1){
    int t=(tid>=o)?sh[tid-o]:0; __syncthreads();
    sh[tid]+=t; __syncthreads();
  }
  if(i<NN) incl[i]=sh[tid];
  if(tid==255) bsum[b]=sh[255];
}
__global__ __launch_bounds__(256) void k_scan3(const int* __restrict__ deg, const int* __restrict__ incl,
                        const int* __restrict__ bsum, int* __restrict__ row_ptr, int* __restrict__ cursor){
  __shared__ int sh[256];
  int b=blockIdx.x, tid=threadIdx.x;
  sh[tid]=(tid<b && tid<NB)?bsum[tid]:0;
  __syncthreads();
  for(int o=128;o>0;o>>=1){ if(tid<o) sh[tid]+=sh[tid+o]; __syncthreads(); }
  int boff=sh[0];
  int i=b*256+tid;
  if(i<NN){
    int r=incl[i]+boff;
    row_ptr[i+1]=r; cursor[i]=r-deg[i];
  }
  if(i==0) row_ptr[0]=0;
}

// CSR fill with source-node + edge-attr materialized in slot order
__global__ void k_fill_csr2(const int* __restrict__ ei, const float* __restrict__ ea,
    int* __restrict__ cursor, int* __restrict__ csr_src, float* __restrict__ eas){
  int e=blockIdx.x*blockDim.x+threadIdx.x;
  if(e<NE){
    int t=ei[NE+e]; int pos=atomicAdd(&cursor[t],1);
    csr_src[pos]=ei[e];
    const float* s=ea+(size_t)e*9;
    float* d=eas+(size_t)pos*12;
    #pragma unroll
    for(int k=0;k<9;++k) d[k]=s[k];
    d[9]=0.f; d[10]=0.f; d[11]=0.f;
  }
}

// stable counting-sort of pairs by type; tiles of 32 rows padded per group; islot = slot->output pos
__global__ __launch_bounds__(256) void k_sort(const int* __restrict__ types, int* __restrict__ meta,
    int* __restrict__ slotp, int* __restrict__ islot){
  __shared__ int cnt[256][8];
  __shared__ int tot[8];
  __shared__ int base_s[8], pad_s[8];
  int tid=threadIdx.x;
  int lc[8]={0,0,0,0,0,0,0,0};
  int tl[32];
  for(int i=0;i<32;++i){ int ty=types[tid*32+i]; tl[i]=ty; lc[ty]++; }
  #pragma unroll
  for(int t=0;t<8;++t) cnt[tid][t]=lc[t];
  __syncthreads();
  if(tid<8){
    int run=0;
    for(int j=0;j<256;++j){ int v=cnt[j][tid]; cnt[j][tid]=run; run+=v; }
    tot[tid]=run;
  }
  __syncthreads();
  if(tid==0){
    int b=0, pb=0, nt=0;
    for(int t=0;t<8;++t){
      base_s[t]=b; pad_s[t]=pb;
      meta[t]=tot[t]; meta[8+t]=b; meta[16+t]=pb;
      int ntt=(tot[t]+31)>>5;
      for(int j=0;j<ntt;++j){ meta[32+nt]=t; meta[32+MAXT+nt]=pb+j*32; nt++; }
      b+=tot[t]; pb+=ntt*32;
    }
    meta[24]=nt; meta[25]=pb;
  }
  __syncthreads();
  if(tid<8){
    int t=tid; int ntt=(tot[t]+31)>>5;
    for(int sr=tot[t]; sr<ntt*32; ++sr) islot[pad_s[t]+sr]=-1;
  }
  int run[8];
  #pragma unroll
  for(int t=0;t<8;++t) run[t]=cnt[tid][t];
  for(int i=0;i<32;++i){
    int p=tid*32+i; int t=tl[i]; int r=run[t]++;
    int pos=base_s[t]+r, slot=pad_s[t]+r;
    slotp[p]=slot; islot[slot]=pos;
  }
}

// node transform: grid 313x8, hsT[k][r] transposed staging -> float4 LDS reads both operands
__global__ __launch_bounds__(256) void k_nodexf(const float* __restrict__ hin,
    const float* __restrict__ Wl, const float* __restrict__ bl,
    const float* __restrict__ Wr, const float* __restrict__ br,
    float* __restrict__ xl, float* __restrict__ xr, int lk){
  __shared__ float hsT[64][68];
  __shared__ float ws[64][68];
  int bid=blockIdx.x;
  int n0=(bid>>3)*64, ch=bid&7;
  const float* W=(ch<4)?Wl:Wr;
  const float* bb=(ch<4)?bl:br;
  float* outp=(ch<4)?xl:xr;
  int c0=(ch&3)*64;
  int tid=threadIdx.x;

  for(int idx=tid; idx<64*16; idx+=256){
    int r=idx&63, kq=idx>>6;
    int n=n0+r;
    float4 v=make_float4(0.f,0.f,0.f,0.f);
    if(n<NN) v=*(const float4*)&hin[(size_t)n*64+kq*4];
    if(lk){
      v.x=v.x>0.f?v.x:0.01f*v.x; v.y=v.y>0.f?v.y:0.01f*v.y;
      v.z=v.z>0.f?v.z:0.01f*v.z; v.w=v.w>0.f?v.w:0.01f*v.w;
    }
    hsT[kq*4+0][r]=v.x; hsT[kq*4+1][r]=v.y; hsT[kq*4+2][r]=v.z; hsT[kq*4+3][r]=v.w;
  }
  for(int idx=tid; idx<64*16; idx+=256){
    int k=idx>>4, j4=idx&15;
    *(float4*)&ws[k][j4*4]=*(const float4*)&W[(size_t)k*256+c0+j4*4];
  }
  __syncthreads();

  int ty=tid>>4, tx=tid&15;
  float acc[4][4]={};
  #pragma unroll 4
  for(int k=0;k<64;++k){
    float4 a=*(const float4*)&hsT[k][4*ty];
    float4 b=*(const float4*)&ws[k][4*tx];
    float aa[4]={a.x,a.y,a.z,a.w}, bbv[4]={b.x,b.y,b.z,b.w};
    #pragma unroll
    for(int i=0;i<4;++i){
      #pragma unroll
      for(int j=0;j<4;++j) acc[i][j]=fmaf(aa[i],bbv[j],acc[i][j]);
    }
  }
  float4 bias4=*(const float4*)&bb[c0+4*tx];
  #pragma unroll
  for(int i=0;i<4;++i){
    int n=n0+4*ty+i;
    if(n<NN){
      float4 o=make_float4(acc[i][0]+bias4.x, acc[i][1]+bias4.y, acc[i][2]+bias4.z, acc[i][3]+bias4.w);
      *(float4*)&outp[(size_t)n*256+c0+4*tx]=o;
    }
  }
}

// fused GAT edge pipeline (round-11 proven): sequential csr_src/eas streams +
// depth-4 rolling xl prefetch + DPP wave-sum
__global__ __launch_bounds__(256) void k_agg2(const float* __restrict__ xl, const float* __restrict__ xr,
    const float* __restrict__ eas, const int* __restrict__ csr_src, const int* __restrict__ row_ptr,
    const float* __restrict__ WeL, const float* __restrict__ attL,
    const float* __restrict__ biasL, const float* __restrict__ gates, int layer,
    const float* __restrict__ hprev, float* __restrict__ hout){
  __shared__ float red[4][64];
  int n=blockIdx.x, tid=threadIdx.x;
  float w0=WeL[tid],      w1=WeL[256+tid],  w2=WeL[512+tid],  w3=WeL[768+tid],  w4=WeL[1024+tid];
  float w5=WeL[1280+tid], w6=WeL[1536+tid], w7=WeL[1792+tid], w8=WeL[2048+tid];
  float att_t=attL[tid];
  float xr_t=xr[(size_t)n*256+tid];
  int s=row_ptr[n], t=row_ptr[n+1];
  float den=0.f, acc=0.f;

  auto body=[&](float xlv, int j){
    const float4* ep=(const float4*)(eas+(size_t)j*12);
    float4 e0=ep[0], e1=ep[1];
    float e8=eas[(size_t)j*12+8];
    float ev=e0.x*w0+e0.y*w1+e0.z*w2+e0.w*w3+e1.x*w4+e1.y*w5+e1.z*w6+e1.w*w7+e8*w8;
    float m=xlv+xr_t+ev;
    m=m>0.f?m:0.2f*m;
    float pt=dpp_sum64(m*att_t);
    float a=__expf(pt);
    den+=a; acc+=a*xlv;
  };

  float x0=0.f,x1=0.f,x2=0.f,x3=0.f;
  if(s+0<t) x0=xl[(size_t)csr_src[s+0]*256+tid];
  if(s+1<t) x1=xl[(size_t)csr_src[s+1]*256+tid];
  if(s+2<t) x2=xl[(size_t)csr_src[s+2]*256+tid];
  if(s+3<t) x3=xl[(size_t)csr_src[s+3]*256+tid];
  int j=s;
  while(j+7<t){
    float y0=xl[(size_t)csr_src[j+4]*256+tid];
    float y1=xl[(size_t)csr_src[j+5]*256+tid];
    float y2=xl[(size_t)csr_src[j+6]*256+tid];
    float y3=xl[(size_t)csr_src[j+7]*256+tid];
    body(x0,j); body(x1,j+1); body(x2,j+2); body(x3,j+3);
    x0=y0; x1=y1; x2=y2; x3=y3;
    j+=4;
  }
  if(j<t){ body(x0,j); ++j; }
  if(j<t){ body(x1,j); ++j; }
  if(j<t){ body(x2,j); ++j; }
  if(j<t){ body(x3,j); ++j; }
  while(j<t){ body(xl[(size_t)csr_src[j]*256+tid], j); ++j; }

  float rdn=den>0.f?1.f/den:0.f;
  int h=tid>>6, cc=tid&63;
  red[h][cc]=acc*rdn;
  __syncthreads();
  if(tid<64){
    float mean=(red[0][tid]+red[1][tid]+red[2][tid]+red[3][tid])*0.25f + biasL[tid];
    float o;
    if(layer==0) o=mean;
    else{
      float hp=hprev[(size_t)n*64+tid];
      hp=hp>0.f?hp:0.01f*hp;
      float g=sigm(gates[layer-1]);
      o=g*mean+(1.f-g)*hp;
    }
    hout[(size_t)n*64+tid]=o;
  }
}

// z0[slot, 2c]=h[a,c], z0[slot,2c+1]=h[b,c]
__global__ void k_buildz(const float* __restrict__ hfin, const int* __restrict__ ecross,
    const int* __restrict__ slotp, float* __restrict__ z){
  int g=blockIdx.x*blockDim.x+threadIdx.x;
  if(g>=NP*64) return;
  int p=g>>6, c=g&63;
  int a=ecross[2*p], b=ecross[2*p+1];
  int slot=slotp[p];
  float2 v; v.x=hfin[(size_t)a*64+c]; v.y=hfin[(size_t)b*64+c];
  ((float2*)(z+(size_t)slot*128))[c]=v;
}

// W1 prep: per (er, chunk of 32 j): chunk-linear fp16 image [jl(32)][k(128)] with
// XOR swizzle ((jl*128+k) ^ ((jl&7)<<3)) baked in -> global_load_lds drops it verbatim.
__global__ __launch_bounds__(256) void k_prepw1(const float* __restrict__ src, _Float16* __restrict__ dst){
  __shared__ float lds[128][33];
  int bid=blockIdx.x, er=bid>>7, ch=bid&127;
  const float* s=src+(size_t)er*128*4096 + ch*32;
  int tid=threadIdx.x;
  for(int idx=tid; idx<128*32; idx+=256){ int k=idx>>5, jl=idx&31; lds[k][jl]=s[(size_t)k*4096+jl]; }
  __syncthreads();
  _Float16* d=dst+(size_t)bid*4096;
  for(int g=tid; g<512; g+=256){
    int jl=g>>4, k8=g&15;
    f16x8 v;
    #pragma unroll
    for(int t=0;t<8;++t) v[t]=(_Float16)lds[k8*8+t][jl];
    int elem=(jl*128+k8*8)^((jl&7)<<3);
    *(f16x8*)(&d[elem])=v;
  }
}

// W2 prep: per (er, chunk of 32 j): [n(128)][jl(32)] with XOR swizzle ((n*32+jl) ^ ((n&7)<<3)).
__global__ __launch_bounds__(256) void k_prepw2(const float* __restrict__ src, _Float16* __restrict__ dst){
  __shared__ float lds[32][130];
  int bid=blockIdx.x, er=bid>>7, ch=bid&127;
  const float* s=src+(size_t)er*4096*128 + (size_t)ch*32*128;
  int tid=threadIdx.x;
  for(int idx=tid; idx<32*128; idx+=256){ int j=idx>>7, n=idx&127; lds[j][n]=s[(size_t)j*128+n]; }
  __syncthreads();
  _Float16* d=dst+(size_t)bid*4096;
  for(int g=tid; g<512; g+=256){
    int n=g>>2, j8=g&3;
    f16x8 v;
    #pragma unroll
    for(int t=0;t<8;++t) v[t]=(_Float16)lds[j8*8+t][n];
    int elem=(n*32+j8*8)^((n&7)<<3);
    *(f16x8*)(&d[elem])=v;
  }
}

// MFMA res-block partial: ypart[hq] = relu(relu(z)@W1[:,hq-range]+b1) @ W2[hq-range,:]
// v2 schedule: 2 barriers/chunk (ts double-buffered; GLL issue after barrier A)
__global__ __launch_bounds__(256) void k_resmfma(const float* __restrict__ zin,
    const _Float16* __restrict__ w1t, const _Float16* __restrict__ w2t,
    const float* __restrict__ b1all, const int* __restrict__ meta,
    float* __restrict__ ypart, int rb)
{
  __shared__ _Float16 zh[32*128];
  __shared__ _Float16 wb[2][8192];
  __shared__ _Float16 ts[2][32*32];
  __shared__ float b1s[1024];
  int bidl=blockIdx.x;
  int bid=(bidl&7)*132+(bidl>>3);
  int v=bid>>2, hq=bid&3;
  int nt=meta[24];
  if(v>=nt) return;
  int e=meta[32+v], row0=meta[32+MAXT+v];
  int er=e*2+rb;
  const _Float16* w1b=w1t+(size_t)er*524288 + (size_t)hq*32*4096;
  const _Float16* w2b=w2t+(size_t)er*524288 + (size_t)hq*32*4096;
  const float* b1g=b1all+(size_t)er*4096 + hq*1024;
  int tid=threadIdx.x, l=tid&63, w=tid>>6;
  int lm=l&15, lq=l>>4;
  int s16=(w&1)*16, jh=w>>1;
  int arow=s16+lm;

  for(int g=tid; g<512; g+=256){
    int row=g>>4, slot=g&15;
    const float* src=zin+(size_t)(row0+row)*128+slot*8;
    float4 v0=*(const float4*)src;
    float4 v1=*(const float4*)(src+4);
    f16x8 hv;
    hv[0]=(_Float16)fmaxf(v0.x,0.f); hv[1]=(_Float16)fmaxf(v0.y,0.f);
    hv[2]=(_Float16)fmaxf(v0.z,0.f); hv[3]=(_Float16)fmaxf(v0.w,0.f);
    hv[4]=(_Float16)fmaxf(v1.x,0.f); hv[5]=(_Float16)fmaxf(v1.y,0.f);
    hv[6]=(_Float16)fmaxf(v1.z,0.f); hv[7]=(_Float16)fmaxf(v1.w,0.f);
    *(f16x8*)(&zh[(row*128+slot*8)^((row&7)<<3)])=hv;
  }
  for(int g=tid; g<1024; g+=256) b1s[g]=b1g[g];

  // prologue: issue chunk 0 loads
  #pragma unroll
  for(int s=0;s<2;++s){
    int so=(w*2+s)*512;
    GLL16(w1b+so+l*8, &wb[0][so]);
    GLL16(w2b+so+l*8, &wb[0][4096+so]);
  }
  asm volatile("s_waitcnt lgkmcnt(0)" ::: "memory");
  __builtin_amdgcn_sched_barrier(0);
  __builtin_amdgcn_s_barrier();        // zh/b1s visible; chunk0 loads in flight

  f32x4 yacc[4];
  #pragma unroll
  for(int i=0;i<4;++i){ yacc[i][0]=0.f; yacc[i][1]=0.f; yacc[i][2]=0.f; yacc[i][3]=0.f; }

  for(int cc=0; cc<32; ++cc){
    int buf=cc&1;
    asm volatile("s_waitcnt vmcnt(0)" ::: "memory");   // this wave's chunk-cc loads landed
    __builtin_amdgcn_sched_barrier(0);
    __builtin_amdgcn_s_barrier();      // A: wb[buf] complete across waves; prior reads of wb[buf^1..] retired
    if(cc<31){
      const _Float16* g1=w1b+(size_t)(cc+1)*4096;
      const _Float16* g2=w2b+(size_t)(cc+1)*4096;
      int nb=buf^1;
      #pragma unroll
      for(int s=0;s<2;++s){
        int so=(w*2+s)*512;
        GLL16(g1+so+l*8, &wb[nb][so]);
        GLL16(g2+so+l*8, &wb[nb][4096+so]);
      }
    }

    // GEMM1: t[32 x 32j] = relu(z) @ W1chunk   (K=128)
    f32x4 tacc={0.f,0.f,0.f,0.f};
    int j=jh*16+lm;
    #pragma unroll
    for(int ks=0;ks<4;++ks){
      f16x8 a=*(const f16x8*)(&zh[(arow*128+ks*32+lq*8)^((arow&7)<<3)]);
      f16x8 b=*(const f16x8*)(&wb[buf][(j*128+ks*32+lq*8)^((j&7)<<3)]);
      tacc=__builtin_amdgcn_mfma_f32_16x16x32_f16(a,b,tacc,0,0,0);
    }
    float b1v=b1s[cc*32+j];
    #pragma unroll
    for(int r=0;r<4;++r){
      int trow=s16+lq*4+r;
      ts[buf][(trow*32+j)^((trow&7)<<3)]=(_Float16)fmaxf(tacc[r]+b1v,0.f);
    }
    asm volatile("s_waitcnt lgkmcnt(0)" ::: "memory");
    __builtin_amdgcn_sched_barrier(0);
    __builtin_amdgcn_s_barrier();      // B: ts[buf] visible

    // GEMM2: y[32 x 128] += t @ W2chunk   (K=32)
    f16x8 a2=*(const f16x8*)(&ts[buf][(arow*32+lq*8)^((arow&7)<<3)]);
    #pragma unroll
    for(int nf=0;nf<4;++nf){
      int n=jh*64+nf*16+lm;
      f16x8 b=*(const f16x8*)(&wb[buf][4096+((n*32+lq*8)^((n&7)<<3))]);
      yacc[nf]=__builtin_amdgcn_mfma_f32_16x16x32_f16(a2,b,yacc[nf],0,0,0);
    }
    // no trailing barrier: wb[buf]/ts[buf] next written only after a future barrier A
  }

  float* yp=ypart+(size_t)hq*CAPR*128;
  #pragma unroll
  for(int nf=0;nf<4;++nf){
    int col=jh*64+nf*16+lm;
    #pragma unroll
    for(int r=0;r<4;++r)
      yp[(size_t)(row0+s16+lq*4+r)*128+col]=yacc[nf][r];
  }
}

// combine 4 hid-quadrant partials + gated residual; rb==1 fuses head dot + ordered scatter
__global__ __launch_bounds__(256) void k_comb(const float* __restrict__ zin, const float* __restrict__ ypart,
    const float* __restrict__ b2all, const float* __restrict__ gates, const int* __restrict__ meta,
    int rb, float* __restrict__ zout,
    const float* __restrict__ hWg, const float* __restrict__ hbg, const int* __restrict__ islot,
    float* __restrict__ out)
{
  int v=blockIdx.x;
  if(v>=meta[24]) return;
  int e=meta[32+v], row0=meta[32+MAXT+v];
  int er=e*2+rb;
  float ge=sigm(gates[er]);
  const float* b2=b2all+(size_t)er*128;
  int tid=threadIdx.x;
  const size_t HS=(size_t)CAPR*128;
  if(rb==0){
    for(int idx=tid; idx<32*128; idx+=256){
      int r=idx>>7, c=idx&127;
      size_t o=(size_t)(row0+r)*128+c;
      float y=ypart[o]+ypart[HS+o]+ypart[2*HS+o]+ypart[3*HS+o];
      float zr=fmaxf(zin[o],0.f);
      zout[o]=ge*(y+b2[c])+(1.f-ge)*zr;
    }
  }else{
    int r=tid>>3, cs=tid&7;
    float acc=0.f;
    size_t ro=(size_t)(row0+r)*128;
    #pragma unroll
    for(int q=0;q<16;++q){
      int c=cs*16+q;
      size_t o=ro+c;
      float y=ypart[o]+ypart[HS+o]+ypart[2*HS+o]+ypart[3*HS+o];
      float zr=fmaxf(zin[o],0.f);
      float zf=ge*(y+b2[c])+(1.f-ge)*zr;
      acc+=zf*hWg[e*128+c];
    }
    acc+=__shfl_xor(acc,1); acc+=__shfl_xor(acc,2); acc+=__shfl_xor(acc,4);
    if(cs==0){
      int pos=islot[row0+r];
      if(pos>=0) out[pos]=acc+hbg[e];
    }
  }
}

extern "C" void kernel_launch(void* const* d_in, const int* in_sizes, int n_in,
                              void* d_out, int out_size, void* d_ws, size_t ws_size,
                              hipStream_t stream){
  const float* x     =(const float*)d_in[0];
  const int*   ei    =(const int*)  d_in[1];
  const float* ea    =(const float*)d_in[2];
  const int*   ecross=(const int*)  d_in[3];
  const int*   types =(const int*)  d_in[4];
  const float* gWl   =(const float*)d_in[5];
  const float* gbl   =(const float*)d_in[6];
  const float* gWr   =(const float*)d_in[7];
  const float* gbr   =(const float*)d_in[8];
  const float* gWe   =(const float*)d_in[9];
  const float* gatt  =(const float*)d_in[10];
  const float* gbias =(const float*)d_in[11];
  const float* ggate =(const float*)d_in[12];
  const float* rW1   =(const float*)d_in[13];
  const float* rb1   =(const float*)d_in[14];
  const float* rW2   =(const float*)d_in[15];
  const float* rb2   =(const float*)d_in[16];
  const float* rg    =(const float*)d_in[17];
  const float* hW    =(const float*)d_in[18];
  const float* hb    =(const float*)d_in[19];
  float* out=(float*)d_out;

  char* base=(char*)d_ws;
  size_t off=0;
  auto alloc=[&](size_t bytes)->char*{
    char* p=base+off;
    off=(off+bytes+511)&~((size_t)511);
    return p;
  };
  float* hA     =(float*)alloc((size_t)NN*64*4);
  float* hB     =(float*)alloc((size_t)NN*64*4);   // reused as zB in expert phase
  int*   deg    =(int*)  alloc((size_t)NN*4);
  int*   row_ptr=(int*)  alloc((size_t)(NN+1)*4);
  int*   cursor =(int*)  alloc((size_t)NN*4);
  int*   incl   =(int*)  alloc((size_t)NN*4);
  int*   bsum   =(int*)  alloc(256*4);
  int*   csr_src=(int*)  alloc((size_t)(NE+16)*4);
  int*   meta   =(int*)  alloc(1024*4);
  int*   slotp  =(int*)  alloc((size_t)NP*4);
  int*   islot  =(int*)  alloc((size_t)CAPR*4);
  float* zA     =(float*)alloc((size_t)CAPR*128*4);
  // union region: {xl, xr, eas} (GAT) overlaid with {w1t, w2t, ypart} (experts)
  size_t uoff=off;
  float* xl =(float*)(base+uoff);
  float* xr =(float*)(base+uoff+(size_t)NN*256*4);
  float* eas=(float*)(base+uoff+(size_t)NN*256*4*2);
  _Float16* w1t=(_Float16*)(base+uoff);
  _Float16* w2t=(_Float16*)(base+uoff+(size_t)16*524288*2);
  float* ypart =(float*)(base+uoff+(size_t)16*524288*2*2);
  size_t gat_bytes=(size_t)NN*256*4*2 + (size_t)(NE*12+16)*4;
  size_t exp_bytes=(size_t)16*524288*2*2 + (size_t)4*CAPR*128*4;
  size_t need=uoff+(gat_bytes>exp_bytes?gat_bytes:exp_bytes);
  if(ws_size<need) return;
  float* zB=hB;

  // ---- CSR by target (+src/ea materialization) + pair sort ----
  hipMemsetAsync(deg,0,(size_t)NN*4,stream);
  k_deg<<<(NE+255)/256,256,0,stream>>>(ei,deg);
  k_scan1<<<NB,256,0,stream>>>(deg,incl,bsum);
  k_scan3<<<NB,256,0,stream>>>(deg,incl,bsum,row_ptr,cursor);
  k_fill_csr2<<<(NE+255)/256,256,0,stream>>>(ei,ea,cursor,csr_src,eas);
  k_sort<<<1,256,0,stream>>>(types,meta,slotp,islot);

  // ---- GAT layers ----
  const float* hcur=x;
  float* hnext=hA;
  for(int L=0;L<NL;++L){
    k_nodexf<<<((NN+63)/64)*8,256,0,stream>>>(hcur, gWl+(size_t)L*64*256, gbl+(size_t)L*256,
                                              gWr+(size_t)L*64*256, gbr+(size_t)L*256, xl, xr, L>0?1:0);
    k_agg2<<<NN,256,0,stream>>>(xl,xr,eas,csr_src,row_ptr, gWe+(size_t)L*EDIM*256,
                                gatt+(size_t)L*256, gbias+(size_t)L*64, ggate, L, hcur, hnext);
    hcur=hnext;
    hnext=(hcur==hA)?hB:hA;
  }
  // hcur == hA after 3 layers; hB is dead -> zB overlay is safe

  // ---- pair gather into type-sorted padded layout ----
  k_buildz<<<NP*64/256,256,0,stream>>>(hcur,ecross,slotp,zA);

  // ---- weight prep: fp16, chunked, transposed, swizzle baked in (xl/xr/eas now dead) ----
  k_prepw1<<<2048,256,0,stream>>>(rW1,w1t);
  k_prepw2<<<2048,256,0,stream>>>(rW2,w2t);

  // ---- routed experts: 2 res-blocks, each = MFMA partial + combine ----
  k_resmfma<<<1056,256,0,stream>>>(zA,w1t,w2t,rb1,meta,ypart,0);
  k_comb<<<MAXT,256,0,stream>>>(zA,ypart,rb2,rg,meta,0,zB,hW,hb,islot,out);
  k_resmfma<<<1056,256,0,stream>>>(zB,w1t,w2t,rb1,meta,ypart,1);
  k_comb<<<MAXT,256,0,stream>>>(zB,ypart,rb2,rg,meta,1,zA,hW,hb,islot,out);

  (void)in_sizes; (void)n_in; (void)out_size;
}